// Round 1
// baseline (526.829 us; speedup 1.0000x reference)
//
#include <hip/hip_runtime.h>
#include <math.h>

#define N_NODES   100000
#define N_EDGES   1600000
#define E_TOT     (N_EDGES + N_NODES)
#define N_FEAT    512
#define HEADS     8
#define F_HEAD    8
#define HIDDEN    64
#define N_CLASSES 40

// ============================ CSR build ============================

__global__ void k_hist(const int* __restrict__ ei, int* __restrict__ cnt) {
  int e = blockIdx.x * blockDim.x + threadIdx.x;
  int stride = gridDim.x * blockDim.x;
  for (; e < E_TOT; e += stride) {
    int dst = (e < N_EDGES) ? ei[N_EDGES + e] : (e - N_EDGES);
    atomicAdd(&cnt[dst], 1);
  }
}

#define SCAN_BLK 256
#define SCAN_ITEMS 8
#define SCAN_TILE (SCAN_BLK * SCAN_ITEMS)                   // 2048
#define SCAN_NBLK ((N_NODES + SCAN_TILE - 1) / SCAN_TILE)   // 49

__global__ void k_scanA(const int* __restrict__ cnt, int* __restrict__ bsum) {
  __shared__ int red[SCAN_BLK];
  int t = threadIdx.x, b = blockIdx.x;
  int base = b * SCAN_TILE + t * SCAN_ITEMS;
  int s = 0;
#pragma unroll
  for (int i = 0; i < SCAN_ITEMS; ++i) {
    int idx = base + i;
    if (idx < N_NODES) s += cnt[idx];
  }
  red[t] = s;
  __syncthreads();
  for (int off = SCAN_BLK / 2; off > 0; off >>= 1) {
    if (t < off) red[t] += red[t + off];
    __syncthreads();
  }
  if (t == 0) bsum[b] = red[0];
}

__global__ void k_scanB(const int* __restrict__ bsum, int* __restrict__ boff,
                        int* __restrict__ rowp) {
  if (threadIdx.x == 0) {
    int acc = 0;
    for (int b = 0; b < SCAN_NBLK; ++b) { boff[b] = acc; acc += bsum[b]; }
    rowp[N_NODES] = acc;   // == E_TOT
  }
}

__global__ void k_scanC(const int* __restrict__ cnt, const int* __restrict__ boff,
                        int* __restrict__ rowp, int* __restrict__ cursor) {
  __shared__ int red[SCAN_BLK];
  int t = threadIdx.x, b = blockIdx.x;
  int base = b * SCAN_TILE + t * SCAN_ITEMS;
  int v[SCAN_ITEMS];
  int s = 0;
#pragma unroll
  for (int i = 0; i < SCAN_ITEMS; ++i) {
    int idx = base + i;
    v[i] = (idx < N_NODES) ? cnt[idx] : 0;   // all reads of cnt happen before first barrier
    s += v[i];
  }
  red[t] = s;
  __syncthreads();
  // Hillis-Steele inclusive scan
  for (int off = 1; off < SCAN_BLK; off <<= 1) {
    int add = (t >= off) ? red[t - off] : 0;
    __syncthreads();
    red[t] += add;
    __syncthreads();
  }
  int excl = red[t] - s + boff[b];
#pragma unroll
  for (int i = 0; i < SCAN_ITEMS; ++i) {
    int idx = base + i;
    if (idx < N_NODES) { rowp[idx] = excl; cursor[idx] = excl; }
    excl += v[i];
  }
}

__global__ void k_scatter(const int* __restrict__ ei, int* __restrict__ cursor,
                          int* __restrict__ ssrc) {
  int e = blockIdx.x * blockDim.x + threadIdx.x;
  int stride = gridDim.x * blockDim.x;
  for (; e < E_TOT; e += stride) {
    int src, dst;
    if (e < N_EDGES) { src = ei[e]; dst = ei[N_EDGES + e]; }
    else             { src = e - N_EDGES; dst = src; }
    int pos = atomicAdd(&cursor[dst], 1);
    ssrc[pos] = src;
  }
}

// ============================ Layer 1 GEMM: h1 = x @ W1 ============================
// fp32 vector FMA (no fp32 MFMA on CDNA4). 64-node x 64-col tile, BK=8.

#define G1_BM 64
#define G1_BK 8

__global__ __launch_bounds__(256) void k_gemm1(const float* __restrict__ x,
                                               const float* __restrict__ W1,
                                               float* __restrict__ h1) {
  __shared__ __align__(16) float xs[G1_BK][G1_BM + 4];  // pad -> 2-way max on transpose store
  __shared__ __align__(16) float ws[G1_BK][HIDDEN];
  int t = threadIdx.x;
  int n0 = blockIdx.x * G1_BM;
  int tx = t & 15, ty = t >> 4;
  int lrow = t >> 2;            // 0..63  node within tile
  int lk   = (t & 3) * 2;       // 0,2,4,6
  int node = n0 + lrow;
  bool ld = node < N_NODES;
  const float* xp = x + (size_t)node * N_FEAT + lk;
  float acc[4][4];
#pragma unroll
  for (int i = 0; i < 4; ++i)
#pragma unroll
    for (int j = 0; j < 4; ++j) acc[i][j] = 0.f;

  for (int k0 = 0; k0 < N_FEAT; k0 += G1_BK) {
    float2 xv = make_float2(0.f, 0.f);
    if (ld) xv = *(const float2*)(xp + k0);
    float2 wv = *(const float2*)(W1 + k0 * HIDDEN + t * 2);
    __syncthreads();          // previous iteration's LDS reads done
    xs[lk][lrow]     = xv.x;
    xs[lk + 1][lrow] = xv.y;
    ((float2*)&ws[0][0])[t] = wv;
    __syncthreads();
#pragma unroll
    for (int k = 0; k < G1_BK; ++k) {
      float4 a = *(const float4*)&xs[k][ty * 4];
      float4 b = *(const float4*)&ws[k][tx * 4];
      acc[0][0] = fmaf(a.x, b.x, acc[0][0]); acc[0][1] = fmaf(a.x, b.y, acc[0][1]);
      acc[0][2] = fmaf(a.x, b.z, acc[0][2]); acc[0][3] = fmaf(a.x, b.w, acc[0][3]);
      acc[1][0] = fmaf(a.y, b.x, acc[1][0]); acc[1][1] = fmaf(a.y, b.y, acc[1][1]);
      acc[1][2] = fmaf(a.y, b.z, acc[1][2]); acc[1][3] = fmaf(a.y, b.w, acc[1][3]);
      acc[2][0] = fmaf(a.z, b.x, acc[2][0]); acc[2][1] = fmaf(a.z, b.y, acc[2][1]);
      acc[2][2] = fmaf(a.z, b.z, acc[2][2]); acc[2][3] = fmaf(a.z, b.w, acc[2][3]);
      acc[3][0] = fmaf(a.w, b.x, acc[3][0]); acc[3][1] = fmaf(a.w, b.y, acc[3][1]);
      acc[3][2] = fmaf(a.w, b.z, acc[3][2]); acc[3][3] = fmaf(a.w, b.w, acc[3][3]);
    }
  }
#pragma unroll
  for (int i = 0; i < 4; ++i) {
    int nn = n0 + ty * 4 + i;
    if (nn < N_NODES) {
      *(float4*)(h1 + (size_t)nn * HIDDEN + tx * 4) =
          make_float4(acc[i][0], acc[i][1], acc[i][2], acc[i][3]);
    }
  }
}

// ============================ layer-1 attention coefficients ============================

__global__ void k_att1(const float* __restrict__ h1, const float* __restrict__ att_src,
                       const float* __restrict__ att_dst, float* __restrict__ a_src,
                       float* __restrict__ a_dst) {
  int i = blockIdx.x * blockDim.x + threadIdx.x;   // i = node*8 + head
  if (i >= N_NODES * HEADS) return;
  int h = i & 7;
  const float4* hp = (const float4*)(h1 + (size_t)i * F_HEAD);
  float4 v0 = hp[0], v1 = hp[1];
  const float4* sp = (const float4*)(att_src + h * F_HEAD);
  const float4* dp = (const float4*)(att_dst + h * F_HEAD);
  float4 s0 = sp[0], s1 = sp[1], d0 = dp[0], d1 = dp[1];
  float as = v0.x * s0.x + v0.y * s0.y + v0.z * s0.z + v0.w * s0.w +
             v1.x * s1.x + v1.y * s1.y + v1.z * s1.z + v1.w * s1.w;
  float ad = v0.x * d0.x + v0.y * d0.y + v0.z * d0.z + v0.w * d0.w +
             v1.x * d1.x + v1.y * d1.y + v1.z * d1.z + v1.w * d1.w;
  a_src[i] = as;
  a_dst[i] = ad;
}

// ============================ layer-1 edge softmax + aggregate ============================
// one wave per dst node, lane = output column (64). No max-subtraction (|e| <~ 3).

__global__ __launch_bounds__(256) void k_edge1(const int* __restrict__ rowp,
                                               const int* __restrict__ ssrc,
                                               const float* __restrict__ a_src,
                                               const float* __restrict__ a_dst,
                                               const float* __restrict__ h1,
                                               const float* __restrict__ b1,
                                               float* __restrict__ out1) {
  __shared__ float exs[4][64 * 9];   // stride 9: conflict-free-ish stores, conflict-free reads
  __shared__ int   srcs[4][64];
  __shared__ int   mdeg;
  int t = threadIdx.x;
  int wv = t >> 6, lane = t & 63;
  int node = blockIdx.x * 4 + wv;     // grid = N/4 exactly
  int s0 = rowp[node];
  int s1 = rowp[node + 1];
  int deg = s1 - s0;
  if (t == 0) mdeg = 0;
  __syncthreads();
  if (lane == 0) atomicMax(&mdeg, deg);
  __syncthreads();
  int nchunks = (mdeg + 63) >> 6;     // block-uniform so __syncthreads in loop is safe

  float ad[8];
  {
    float4 d0 = *(const float4*)(a_dst + (size_t)node * 8);
    float4 d1 = *(const float4*)(a_dst + (size_t)node * 8 + 4);
    ad[0] = d0.x; ad[1] = d0.y; ad[2] = d0.z; ad[3] = d0.w;
    ad[4] = d1.x; ad[5] = d1.y; ad[6] = d1.z; ad[7] = d1.w;
  }
  float accv = 0.f, dsum = 0.f;
  int hof = lane >> 3;                // head of my column

  for (int c = 0; c < nchunks; ++c) {
    int base = s0 + (c << 6);
    int cn = s1 - base;
    cn = cn < 0 ? 0 : (cn > 64 ? 64 : cn);
    float ex[8];
    int sid = 0;
    if (lane < cn) {
      sid = ssrc[base + lane];
      float4 A0 = *(const float4*)(a_src + (size_t)sid * 8);
      float4 A1 = *(const float4*)(a_src + (size_t)sid * 8 + 4);
      float ea[8] = {A0.x + ad[0], A0.y + ad[1], A0.z + ad[2], A0.w + ad[3],
                     A1.x + ad[4], A1.y + ad[5], A1.z + ad[6], A1.w + ad[7]};
#pragma unroll
      for (int h = 0; h < 8; ++h) {
        float e = ea[h];
        e = e > 0.f ? e : 0.2f * e;    // leaky_relu
        ex[h] = expf(e);
      }
    } else {
#pragma unroll
      for (int h = 0; h < 8; ++h) ex[h] = 0.f;
    }
    __syncthreads();                   // prev chunk's LDS reads done
    srcs[wv][lane] = sid;
#pragma unroll
    for (int h = 0; h < 8; ++h) exs[wv][lane * 9 + h] = ex[h];
    __syncthreads();
    for (int j = 0; j < cn; ++j) {
      float e = exs[wv][j * 9 + hof];            // broadcast within 8-lane head group
      int sj = srcs[wv][j];                      // broadcast
      float hv = h1[(size_t)sj * HIDDEN + lane]; // coalesced 256B gather
      accv = fmaf(e, hv, accv);
      dsum += e;                                 // lane accumulates denom of its head
    }
  }
  float o = accv / (dsum + 1e-16f);
  o += b1[lane];
  o = o > 0.f ? o : expm1f(o);                   // elu
  out1[(size_t)node * HIDDEN + lane] = o;
}

// ============================ Layer 2 GEMM + attention coeffs ============================
// h2 = out1 @ W2 ; a2 = h2 . att2    (thread per node, W2 staged in LDS)

__global__ __launch_bounds__(256) void k_gemm2(const float* __restrict__ out1,
                                               const float* __restrict__ W2,
                                               const float* __restrict__ att_src2,
                                               const float* __restrict__ att_dst2,
                                               float* __restrict__ h2,
                                               float* __restrict__ a_src2,
                                               float* __restrict__ a_dst2) {
  __shared__ __align__(16) float w2s[HIDDEN * N_CLASSES];
  __shared__ float as2[N_CLASSES], ad2[N_CLASSES];
  int t = threadIdx.x;
  for (int i = t; i < HIDDEN * N_CLASSES; i += 256) w2s[i] = W2[i];
  if (t < N_CLASSES) { as2[t] = att_src2[t]; ad2[t] = att_dst2[t]; }
  __syncthreads();
  int node = blockIdx.x * 256 + t;
  if (node >= N_NODES) return;
  const float4* rp = (const float4*)(out1 + (size_t)node * HIDDEN);
  float acc[N_CLASSES];
#pragma unroll
  for (int c = 0; c < N_CLASSES; ++c) acc[c] = 0.f;
  for (int k4 = 0; k4 < 16; ++k4) {
    float4 rv = rp[k4];
#pragma unroll
    for (int kk = 0; kk < 4; ++kk) {
      float r = (kk == 0) ? rv.x : (kk == 1) ? rv.y : (kk == 2) ? rv.z : rv.w;
      const float* wrow = &w2s[(k4 * 4 + kk) * N_CLASSES];
#pragma unroll
      for (int c4 = 0; c4 < 10; ++c4) {
        float4 wvv = *(const float4*)(wrow + c4 * 4);
        acc[c4 * 4 + 0] = fmaf(r, wvv.x, acc[c4 * 4 + 0]);
        acc[c4 * 4 + 1] = fmaf(r, wvv.y, acc[c4 * 4 + 1]);
        acc[c4 * 4 + 2] = fmaf(r, wvv.z, acc[c4 * 4 + 2]);
        acc[c4 * 4 + 3] = fmaf(r, wvv.w, acc[c4 * 4 + 3]);
      }
    }
  }
  float as = 0.f, ad = 0.f;
#pragma unroll
  for (int c = 0; c < N_CLASSES; ++c) {
    as = fmaf(acc[c], as2[c], as);
    ad = fmaf(acc[c], ad2[c], ad);
  }
  float* hp = h2 + (size_t)node * N_CLASSES;
#pragma unroll
  for (int c4 = 0; c4 < 10; ++c4)
    *(float4*)(hp + c4 * 4) =
        make_float4(acc[c4 * 4], acc[c4 * 4 + 1], acc[c4 * 4 + 2], acc[c4 * 4 + 3]);
  a_src2[node] = as;
  a_dst2[node] = ad;
}

// ============================ layer-2 edge softmax + aggregate ============================

__global__ __launch_bounds__(256) void k_edge2(const int* __restrict__ rowp,
                                               const int* __restrict__ ssrc,
                                               const float* __restrict__ a_src,
                                               const float* __restrict__ a_dst,
                                               const float* __restrict__ h2,
                                               const float* __restrict__ b2,
                                               float* __restrict__ out) {
  __shared__ float exs[4][64];
  __shared__ int   srcs[4][64];
  __shared__ int   mdeg;
  int t = threadIdx.x;
  int wv = t >> 6, lane = t & 63;
  int node = blockIdx.x * 4 + wv;
  int s0 = rowp[node];
  int s1 = rowp[node + 1];
  int deg = s1 - s0;
  if (t == 0) mdeg = 0;
  __syncthreads();
  if (lane == 0) atomicMax(&mdeg, deg);
  __syncthreads();
  int nchunks = (mdeg + 63) >> 6;

  float adv = a_dst[node];
  float accv = 0.f, dsum = 0.f;

  for (int c = 0; c < nchunks; ++c) {
    int base = s0 + (c << 6);
    int cn = s1 - base;
    cn = cn < 0 ? 0 : (cn > 64 ? 64 : cn);
    float exv = 0.f;
    int sid = 0;
    if (lane < cn) {
      sid = ssrc[base + lane];
      float e = a_src[sid] + adv;
      e = e > 0.f ? e : 0.2f * e;
      exv = expf(e);
    }
    __syncthreads();
    srcs[wv][lane] = sid;
    exs[wv][lane] = exv;
    __syncthreads();
    for (int j = 0; j < cn; ++j) {
      float e = exs[wv][j];
      dsum += e;
      if (lane < N_CLASSES) {
        int sj = srcs[wv][j];
        accv = fmaf(e, h2[(size_t)sj * N_CLASSES + lane], accv);
      }
    }
  }
  if (lane < N_CLASSES)
    out[(size_t)node * N_CLASSES + lane] = accv / (dsum + 1e-16f) + b2[lane];
}

// ============================ launch ============================

extern "C" void kernel_launch(void* const* d_in, const int* in_sizes, int n_in,
                              void* d_out, int out_size, void* d_ws, size_t ws_size,
                              hipStream_t stream) {
  const float* x        = (const float*)d_in[0];
  const int*   ei       = (const int*)d_in[1];
  const float* W1       = (const float*)d_in[2];
  const float* att_src1 = (const float*)d_in[3];
  const float* att_dst1 = (const float*)d_in[4];
  const float* b1       = (const float*)d_in[5];
  const float* W2       = (const float*)d_in[6];
  const float* att_src2 = (const float*)d_in[7];
  const float* att_dst2 = (const float*)d_in[8];
  const float* b2       = (const float*)d_in[9];
  float* out = (float*)d_out;

  char* w = (char*)d_ws;
  float* h1     = (float*)(w);                    // 25,600,000 B (reused as h2)
  float* out1   = (float*)(w + 25600000);         // 25,600,000 B
  float* a_src1 = (float*)(w + 51200000);         //  3,200,000 B (reused as a_src2/a_dst2)
  float* a_dst1 = (float*)(w + 54400000);         //  3,200,000 B
  int*   rowp   = (int*)(w + 57600000);           //    400,128 B
  int*   cnt    = (int*)(w + 58000128);           //    400,128 B (histogram, then cursor)
  int*   ssrc   = (int*)(w + 58400256);           //  6,800,000 B
  int*   bsum   = (int*)(w + 65200256);           //        256 B
  int*   boff   = (int*)(w + 65200512);           //        256 B
  // total ~65.2 MB

  float* h2     = h1;                  // layer-1 h dead after k_edge1
  float* a_src2 = a_src1;              // layer-1 coeffs dead after k_edge1
  float* a_dst2 = a_src1 + N_NODES;

  // --- CSR build (shared by both layers) ---
  hipMemsetAsync(cnt, 0, (N_NODES + 1) * sizeof(int), stream);
  k_hist<<<2048, 256, 0, stream>>>(ei, cnt);
  k_scanA<<<SCAN_NBLK, SCAN_BLK, 0, stream>>>(cnt, bsum);
  k_scanB<<<1, 64, 0, stream>>>(bsum, boff, rowp);
  k_scanC<<<SCAN_NBLK, SCAN_BLK, 0, stream>>>(cnt, boff, rowp, cnt);
  k_scatter<<<2048, 256, 0, stream>>>(ei, cnt, ssrc);

  // --- layer 1 ---
  k_gemm1<<<(N_NODES + G1_BM - 1) / G1_BM, 256, 0, stream>>>(x, W1, h1);
  k_att1<<<(N_NODES * HEADS + 255) / 256, 256, 0, stream>>>(h1, att_src1, att_dst1, a_src1, a_dst1);
  k_edge1<<<N_NODES / 4, 256, 0, stream>>>(rowp, ssrc, a_src1, a_dst1, h1, b1, out1);

  // --- layer 2 ---
  k_gemm2<<<(N_NODES + 255) / 256, 256, 0, stream>>>(out1, W2, att_src2, att_dst2, h2, a_src2, a_dst2);
  k_edge2<<<N_NODES / 4, 256, 0, stream>>>(rowp, ssrc, a_src2, a_dst2, h2, b2, out);
}

// Round 2
// 497.327 us; speedup vs baseline: 1.0593x; 1.0593x over previous
//
#include <hip/hip_runtime.h>
#include <math.h>

#define N_NODES   100000
#define N_EDGES   1600000
#define E_TOT     (N_EDGES + N_NODES)
#define N_FEAT    512
#define HEADS     8
#define F_HEAD    8
#define HIDDEN    64
#define N_CLASSES 40

typedef __attribute__((ext_vector_type(8))) short short8_t;
typedef __attribute__((ext_vector_type(4))) float f32x4;

// split fp32 -> bf16 hi + bf16 lo (both RNE)
__device__ inline void f2bf2(float x, unsigned short& h, unsigned short& l) {
  union { float f; unsigned u; } a; a.f = x;
  unsigned rh = a.u + 0x7FFFu + ((a.u >> 16) & 1u);
  unsigned short hv = (unsigned short)(rh >> 16);
  union { unsigned u; float f; } hf; hf.u = ((unsigned)hv) << 16;
  union { float f; unsigned u; } b; b.f = x - hf.f;
  unsigned rl = b.u + 0x7FFFu + ((b.u >> 16) & 1u);
  h = hv;
  l = (unsigned short)(rl >> 16);
}

// ============================ CSR build ============================

__global__ void k_hist(const int* __restrict__ ei, int* __restrict__ cnt) {
  int e = blockIdx.x * blockDim.x + threadIdx.x;
  int stride = gridDim.x * blockDim.x;
  for (; e < E_TOT; e += stride) {
    int dst = (e < N_EDGES) ? ei[N_EDGES + e] : (e - N_EDGES);
    atomicAdd(&cnt[dst], 1);
  }
}

#define SCAN_BLK 256
#define SCAN_ITEMS 8
#define SCAN_TILE (SCAN_BLK * SCAN_ITEMS)                   // 2048
#define SCAN_NBLK ((N_NODES + SCAN_TILE - 1) / SCAN_TILE)   // 49

__global__ void k_scanA(const int* __restrict__ cnt, int* __restrict__ bsum) {
  __shared__ int red[SCAN_BLK];
  int t = threadIdx.x, b = blockIdx.x;
  int base = b * SCAN_TILE + t * SCAN_ITEMS;
  int s = 0;
#pragma unroll
  for (int i = 0; i < SCAN_ITEMS; ++i) {
    int idx = base + i;
    if (idx < N_NODES) s += cnt[idx];
  }
  red[t] = s;
  __syncthreads();
  for (int off = SCAN_BLK / 2; off > 0; off >>= 1) {
    if (t < off) red[t] += red[t + off];
    __syncthreads();
  }
  if (t == 0) bsum[b] = red[0];
}

__global__ void k_scanB(const int* __restrict__ bsum, int* __restrict__ boff,
                        int* __restrict__ rowp) {
  if (threadIdx.x == 0) {
    int acc = 0;
    for (int b = 0; b < SCAN_NBLK; ++b) { boff[b] = acc; acc += bsum[b]; }
    rowp[N_NODES] = acc;   // == E_TOT
  }
}

__global__ void k_scanC(const int* __restrict__ cnt, const int* __restrict__ boff,
                        int* __restrict__ rowp, int* __restrict__ cursor) {
  __shared__ int red[SCAN_BLK];
  int t = threadIdx.x, b = blockIdx.x;
  int base = b * SCAN_TILE + t * SCAN_ITEMS;
  int v[SCAN_ITEMS];
  int s = 0;
#pragma unroll
  for (int i = 0; i < SCAN_ITEMS; ++i) {
    int idx = base + i;
    v[i] = (idx < N_NODES) ? cnt[idx] : 0;   // all reads of cnt happen before first barrier
    s += v[i];
  }
  red[t] = s;
  __syncthreads();
  // Hillis-Steele inclusive scan
  for (int off = 1; off < SCAN_BLK; off <<= 1) {
    int add = (t >= off) ? red[t - off] : 0;
    __syncthreads();
    red[t] += add;
    __syncthreads();
  }
  int excl = red[t] - s + boff[b];
#pragma unroll
  for (int i = 0; i < SCAN_ITEMS; ++i) {
    int idx = base + i;
    if (idx < N_NODES) { rowp[idx] = excl; cursor[idx] = excl; }
    excl += v[i];
  }
}

__global__ void k_scatter(const int* __restrict__ ei, int* __restrict__ cursor,
                          int* __restrict__ ssrc) {
  int e = blockIdx.x * blockDim.x + threadIdx.x;
  int stride = gridDim.x * blockDim.x;
  for (; e < E_TOT; e += stride) {
    int src, dst;
    if (e < N_EDGES) { src = ei[e]; dst = ei[N_EDGES + e]; }
    else             { src = e - N_EDGES; dst = src; }
    int pos = atomicAdd(&cursor[dst], 1);
    ssrc[pos] = src;
  }
}

// ============================ W1 -> fragment-ordered bf16 hi/lo ============================
// layout: [ks(16)][ct(4)][lane(64)][e(8)]; element = W1[k][col],
// col = ct*16 + (lane&15), k = ks*32 + (lane>>4)*8 + e.

__global__ void k_w1frag(const float* __restrict__ W1, short* __restrict__ w1fh,
                         short* __restrict__ w1fl) {
  int idx = blockIdx.x * blockDim.x + threadIdx.x;
  if (idx >= N_FEAT * HIDDEN) return;
  int e    = idx & 7;
  int lane = (idx >> 3) & 63;
  int ct   = (idx >> 9) & 3;
  int ks   = idx >> 11;
  int col = ct * 16 + (lane & 15);
  int k   = ks * 32 + (lane >> 4) * 8 + e;
  unsigned short h, l;
  f2bf2(W1[k * HIDDEN + col], h, l);
  w1fh[idx] = (short)h;
  w1fl[idx] = (short)l;
}

// ============================ Layer 1 GEMM: h1 = x @ W1 (split-bf16 MFMA) ============================
// BM=128, BK=64, 4 waves; wave w computes rows [w*32, w*32+32) x 64 cols.
// A staged in LDS in fragment-linear order (conflict-free b128 writes & reads).
// B fragments read directly from fragment-ordered global arrays (L2-resident).

#define G1_BM 128
#define G1_BK 64

__global__ __launch_bounds__(256) void k_gemm1(const float* __restrict__ x,
                                               const short* __restrict__ w1fh,
                                               const short* __restrict__ w1fl,
                                               float* __restrict__ h1) {
  __shared__ __align__(16) short Ah[G1_BM * G1_BK];   // 16 KB
  __shared__ __align__(16) short Al[G1_BM * G1_BK];   // 16 KB
  int t = threadIdx.x;
  int n0 = blockIdx.x * G1_BM;
  int w = t >> 6, l = t & 63;

  f32x4 acc[2][4];
#pragma unroll
  for (int i = 0; i < 2; ++i)
#pragma unroll
    for (int j = 0; j < 4; ++j) acc[i][j] = (f32x4){0.f, 0.f, 0.f, 0.f};

  for (int c = 0; c < N_FEAT / G1_BK; ++c) {
    // ---- stage A tile: 128 rows x 64 k, fragment-linear ----
    if (c) __syncthreads();          // prev chunk's LDS reads done
#pragma unroll
    for (int i = 0; i < 4; ++i) {
      int s = i * 256 + t;           // 16B slot index, wave-contiguous
      int rt = s >> 7, ks = (s >> 6) & 1, ln = s & 63;
      int row = rt * 16 + (ln & 15);
      int kc = ks * 4 + (ln >> 4);
      int node = n0 + row;
      float v[8];
      if (node < N_NODES) {
        const float4* p = (const float4*)(x + (size_t)node * N_FEAT + c * G1_BK + kc * 8);
        float4 v0 = p[0], v1 = p[1];
        v[0] = v0.x; v[1] = v0.y; v[2] = v0.z; v[3] = v0.w;
        v[4] = v1.x; v[5] = v1.y; v[6] = v1.z; v[7] = v1.w;
      } else {
#pragma unroll
        for (int e = 0; e < 8; ++e) v[e] = 0.f;
      }
      short8_t hi, lo;
#pragma unroll
      for (int e = 0; e < 8; ++e) {
        unsigned short hh, ll;
        f2bf2(v[e], hh, ll);
        hi[e] = (short)hh;
        lo[e] = (short)ll;
      }
      *(short8_t*)&Ah[s * 8] = hi;
      *(short8_t*)&Al[s * 8] = lo;
    }
    __syncthreads();
    // ---- compute ----
#pragma unroll
    for (int ks2 = 0; ks2 < 2; ++ks2) {
      int gks = c * 2 + ks2;
      short8_t bh[4], bl[4];
#pragma unroll
      for (int ct = 0; ct < 4; ++ct) {
        bh[ct] = *(const short8_t*)(w1fh + ((size_t)(gks * 4 + ct) * 64 + l) * 8);
        bl[ct] = *(const short8_t*)(w1fl + ((size_t)(gks * 4 + ct) * 64 + l) * 8);
      }
#pragma unroll
      for (int rtl = 0; rtl < 2; ++rtl) {
        int rt = w * 2 + rtl;
        short8_t ah = *(const short8_t*)&Ah[(rt * 128 + ks2 * 64 + l) * 8];
        short8_t al = *(const short8_t*)&Al[(rt * 128 + ks2 * 64 + l) * 8];
#pragma unroll
        for (int ct = 0; ct < 4; ++ct) {
          acc[rtl][ct] = __builtin_amdgcn_mfma_f32_16x16x32_bf16(ah, bh[ct], acc[rtl][ct], 0, 0, 0);
          acc[rtl][ct] = __builtin_amdgcn_mfma_f32_16x16x32_bf16(ah, bl[ct], acc[rtl][ct], 0, 0, 0);
          acc[rtl][ct] = __builtin_amdgcn_mfma_f32_16x16x32_bf16(al, bh[ct], acc[rtl][ct], 0, 0, 0);
        }
      }
    }
  }
  // ---- epilogue: C/D layout col=lane&15, row=(lane>>4)*4+reg ----
#pragma unroll
  for (int rtl = 0; rtl < 2; ++rtl) {
    int rbase = n0 + (w * 2 + rtl) * 16 + (l >> 4) * 4;
    int col0 = l & 15;
#pragma unroll
    for (int ct = 0; ct < 4; ++ct) {
      int col = ct * 16 + col0;
#pragma unroll
      for (int r = 0; r < 4; ++r) {
        int node = rbase + r;
        if (node < N_NODES) h1[(size_t)node * HIDDEN + col] = acc[rtl][ct][r];
      }
    }
  }
}

// ============================ layer-1 attention coefficients ============================

__global__ void k_att1(const float* __restrict__ h1, const float* __restrict__ att_src,
                       const float* __restrict__ att_dst, float* __restrict__ a_src,
                       float* __restrict__ a_dst) {
  int i = blockIdx.x * blockDim.x + threadIdx.x;   // i = node*8 + head
  if (i >= N_NODES * HEADS) return;
  int h = i & 7;
  const float4* hp = (const float4*)(h1 + (size_t)i * F_HEAD);
  float4 v0 = hp[0], v1 = hp[1];
  const float4* sp = (const float4*)(att_src + h * F_HEAD);
  const float4* dp = (const float4*)(att_dst + h * F_HEAD);
  float4 s0 = sp[0], s1 = sp[1], d0 = dp[0], d1 = dp[1];
  float as = v0.x * s0.x + v0.y * s0.y + v0.z * s0.z + v0.w * s0.w +
             v1.x * s1.x + v1.y * s1.y + v1.z * s1.z + v1.w * s1.w;
  float ad = v0.x * d0.x + v0.y * d0.y + v0.z * d0.z + v0.w * d0.w +
             v1.x * d1.x + v1.y * d1.y + v1.z * d1.z + v1.w * d1.w;
  a_src[i] = as;
  a_dst[i] = ad;
}

// ============================ layer-1 edge softmax + aggregate ============================
// one wave per dst node, lane = output column (64). No max-subtraction (|e| <~ 3).

__global__ __launch_bounds__(256) void k_edge1(const int* __restrict__ rowp,
                                               const int* __restrict__ ssrc,
                                               const float* __restrict__ a_src,
                                               const float* __restrict__ a_dst,
                                               const float* __restrict__ h1,
                                               const float* __restrict__ b1,
                                               float* __restrict__ out1) {
  __shared__ float exs[4][64 * 9];   // stride 9: conflict-free-ish stores, conflict-free reads
  __shared__ int   srcs[4][64];
  __shared__ int   mdeg;
  int t = threadIdx.x;
  int wv = t >> 6, lane = t & 63;
  int node = blockIdx.x * 4 + wv;     // grid = N/4 exactly
  int s0 = rowp[node];
  int s1 = rowp[node + 1];
  int deg = s1 - s0;
  if (t == 0) mdeg = 0;
  __syncthreads();
  if (lane == 0) atomicMax(&mdeg, deg);
  __syncthreads();
  int nchunks = (mdeg + 63) >> 6;     // block-uniform so __syncthreads in loop is safe

  float ad[8];
  {
    float4 d0 = *(const float4*)(a_dst + (size_t)node * 8);
    float4 d1 = *(const float4*)(a_dst + (size_t)node * 8 + 4);
    ad[0] = d0.x; ad[1] = d0.y; ad[2] = d0.z; ad[3] = d0.w;
    ad[4] = d1.x; ad[5] = d1.y; ad[6] = d1.z; ad[7] = d1.w;
  }
  float accv = 0.f, dsum = 0.f;
  int hof = lane >> 3;                // head of my column

  for (int c = 0; c < nchunks; ++c) {
    int base = s0 + (c << 6);
    int cn = s1 - base;
    cn = cn < 0 ? 0 : (cn > 64 ? 64 : cn);
    float ex[8];
    int sid = 0;
    if (lane < cn) {
      sid = ssrc[base + lane];
      float4 A0 = *(const float4*)(a_src + (size_t)sid * 8);
      float4 A1 = *(const float4*)(a_src + (size_t)sid * 8 + 4);
      float ea[8] = {A0.x + ad[0], A0.y + ad[1], A0.z + ad[2], A0.w + ad[3],
                     A1.x + ad[4], A1.y + ad[5], A1.z + ad[6], A1.w + ad[7]};
#pragma unroll
      for (int h = 0; h < 8; ++h) {
        float e = ea[h];
        e = e > 0.f ? e : 0.2f * e;    // leaky_relu
        ex[h] = expf(e);
      }
    } else {
#pragma unroll
      for (int h = 0; h < 8; ++h) ex[h] = 0.f;
    }
    __syncthreads();                   // prev chunk's LDS reads done
    srcs[wv][lane] = sid;
#pragma unroll
    for (int h = 0; h < 8; ++h) exs[wv][lane * 9 + h] = ex[h];
    __syncthreads();
    for (int j = 0; j < cn; ++j) {
      float e = exs[wv][j * 9 + hof];            // broadcast within 8-lane head group
      int sj = srcs[wv][j];                      // broadcast
      float hv = h1[(size_t)sj * HIDDEN + lane]; // coalesced 256B gather
      accv = fmaf(e, hv, accv);
      dsum += e;                                 // lane accumulates denom of its head
    }
  }
  float o = accv / (dsum + 1e-16f);
  o += b1[lane];
  o = o > 0.f ? o : expm1f(o);                   // elu
  out1[(size_t)node * HIDDEN + lane] = o;
}

// ============================ Layer 2 GEMM + attention coeffs ============================
// h2 = out1 @ W2 ; a2 = h2 . att2    (thread per node, W2 staged in LDS)

__global__ __launch_bounds__(256) void k_gemm2(const float* __restrict__ out1,
                                               const float* __restrict__ W2,
                                               const float* __restrict__ att_src2,
                                               const float* __restrict__ att_dst2,
                                               float* __restrict__ h2,
                                               float* __restrict__ a_src2,
                                               float* __restrict__ a_dst2) {
  __shared__ __align__(16) float w2s[HIDDEN * N_CLASSES];
  __shared__ float as2[N_CLASSES], ad2[N_CLASSES];
  int t = threadIdx.x;
  for (int i = t; i < HIDDEN * N_CLASSES; i += 256) w2s[i] = W2[i];
  if (t < N_CLASSES) { as2[t] = att_src2[t]; ad2[t] = att_dst2[t]; }
  __syncthreads();
  int node = blockIdx.x * 256 + t;
  if (node >= N_NODES) return;
  const float4* rp = (const float4*)(out1 + (size_t)node * HIDDEN);
  float acc[N_CLASSES];
#pragma unroll
  for (int c = 0; c < N_CLASSES; ++c) acc[c] = 0.f;
  for (int k4 = 0; k4 < 16; ++k4) {
    float4 rv = rp[k4];
#pragma unroll
    for (int kk = 0; kk < 4; ++kk) {
      float r = (kk == 0) ? rv.x : (kk == 1) ? rv.y : (kk == 2) ? rv.z : rv.w;
      const float* wrow = &w2s[(k4 * 4 + kk) * N_CLASSES];
#pragma unroll
      for (int c4 = 0; c4 < 10; ++c4) {
        float4 wvv = *(const float4*)(wrow + c4 * 4);
        acc[c4 * 4 + 0] = fmaf(r, wvv.x, acc[c4 * 4 + 0]);
        acc[c4 * 4 + 1] = fmaf(r, wvv.y, acc[c4 * 4 + 1]);
        acc[c4 * 4 + 2] = fmaf(r, wvv.z, acc[c4 * 4 + 2]);
        acc[c4 * 4 + 3] = fmaf(r, wvv.w, acc[c4 * 4 + 3]);
      }
    }
  }
  float as = 0.f, ad = 0.f;
#pragma unroll
  for (int c = 0; c < N_CLASSES; ++c) {
    as = fmaf(acc[c], as2[c], as);
    ad = fmaf(acc[c], ad2[c], ad);
  }
  float* hp = h2 + (size_t)node * N_CLASSES;
#pragma unroll
  for (int c4 = 0; c4 < 10; ++c4)
    *(float4*)(hp + c4 * 4) =
        make_float4(acc[c4 * 4], acc[c4 * 4 + 1], acc[c4 * 4 + 2], acc[c4 * 4 + 3]);
  a_src2[node] = as;
  a_dst2[node] = ad;
}

// ============================ layer-2 edge softmax + aggregate ============================

__global__ __launch_bounds__(256) void k_edge2(const int* __restrict__ rowp,
                                               const int* __restrict__ ssrc,
                                               const float* __restrict__ a_src,
                                               const float* __restrict__ a_dst,
                                               const float* __restrict__ h2,
                                               const float* __restrict__ b2,
                                               float* __restrict__ out) {
  __shared__ float exs[4][64];
  __shared__ int   srcs[4][64];
  __shared__ int   mdeg;
  int t = threadIdx.x;
  int wv = t >> 6, lane = t & 63;
  int node = blockIdx.x * 4 + wv;
  int s0 = rowp[node];
  int s1 = rowp[node + 1];
  int deg = s1 - s0;
  if (t == 0) mdeg = 0;
  __syncthreads();
  if (lane == 0) atomicMax(&mdeg, deg);
  __syncthreads();
  int nchunks = (mdeg + 63) >> 6;

  float adv = a_dst[node];
  float accv = 0.f, dsum = 0.f;

  for (int c = 0; c < nchunks; ++c) {
    int base = s0 + (c << 6);
    int cn = s1 - base;
    cn = cn < 0 ? 0 : (cn > 64 ? 64 : cn);
    float exv = 0.f;
    int sid = 0;
    if (lane < cn) {
      sid = ssrc[base + lane];
      float e = a_src[sid] + adv;
      e = e > 0.f ? e : 0.2f * e;
      exv = expf(e);
    }
    __syncthreads();
    srcs[wv][lane] = sid;
    exs[wv][lane] = exv;
    __syncthreads();
    for (int j = 0; j < cn; ++j) {
      float e = exs[wv][j];
      dsum += e;
      if (lane < N_CLASSES) {
        int sj = srcs[wv][j];
        accv = fmaf(e, h2[(size_t)sj * N_CLASSES + lane], accv);
      }
    }
  }
  if (lane < N_CLASSES)
    out[(size_t)node * N_CLASSES + lane] = accv / (dsum + 1e-16f) + b2[lane];
}

// ============================ launch ============================

extern "C" void kernel_launch(void* const* d_in, const int* in_sizes, int n_in,
                              void* d_out, int out_size, void* d_ws, size_t ws_size,
                              hipStream_t stream) {
  const float* x        = (const float*)d_in[0];
  const int*   ei       = (const int*)d_in[1];
  const float* W1       = (const float*)d_in[2];
  const float* att_src1 = (const float*)d_in[3];
  const float* att_dst1 = (const float*)d_in[4];
  const float* b1       = (const float*)d_in[5];
  const float* W2       = (const float*)d_in[6];
  const float* att_src2 = (const float*)d_in[7];
  const float* att_dst2 = (const float*)d_in[8];
  const float* b2       = (const float*)d_in[9];
  float* out = (float*)d_out;

  char* w = (char*)d_ws;
  float* h1     = (float*)(w);                    // 25,600,000 B (reused as h2)
  float* out1   = (float*)(w + 25600000);         // 25,600,000 B
  float* a_src1 = (float*)(w + 51200000);         //  3,200,000 B (reused as a_src2/a_dst2)
  float* a_dst1 = (float*)(w + 54400000);         //  3,200,000 B
  int*   rowp   = (int*)(w + 57600000);           //    400,128 B
  int*   cnt    = (int*)(w + 58000128);           //    400,128 B (histogram, then cursor)
  int*   ssrc   = (int*)(w + 58400256);           //  6,800,000 B
  int*   bsum   = (int*)(w + 65200256);           //        256 B
  int*   boff   = (int*)(w + 65200512);           //        256 B
  short* w1fh   = (short*)(w + 65200768);         //     65,536 B (frag-ordered W1 hi)
  short* w1fl   = (short*)(w + 65266304);         //     65,536 B (frag-ordered W1 lo)
  // total ~65.33 MB

  float* h2     = h1;                  // layer-1 h dead after k_edge1
  float* a_src2 = a_src1;              // layer-1 coeffs dead after k_edge1
  float* a_dst2 = a_src1 + N_NODES;

  // --- W1 fragment precompute + CSR build (shared by both layers) ---
  k_w1frag<<<(N_FEAT * HIDDEN + 255) / 256, 256, 0, stream>>>(W1, w1fh, w1fl);
  hipMemsetAsync(cnt, 0, (N_NODES + 1) * sizeof(int), stream);
  k_hist<<<2048, 256, 0, stream>>>(ei, cnt);
  k_scanA<<<SCAN_NBLK, SCAN_BLK, 0, stream>>>(cnt, bsum);
  k_scanB<<<1, 64, 0, stream>>>(bsum, boff, rowp);
  k_scanC<<<SCAN_NBLK, SCAN_BLK, 0, stream>>>(cnt, boff, rowp, cnt);
  k_scatter<<<2048, 256, 0, stream>>>(ei, cnt, ssrc);

  // --- layer 1 ---
  k_gemm1<<<(N_NODES + G1_BM - 1) / G1_BM, 256, 0, stream>>>(x, w1fh, w1fl, h1);
  k_att1<<<(N_NODES * HEADS + 255) / 256, 256, 0, stream>>>(h1, att_src1, att_dst1, a_src1, a_dst1);
  k_edge1<<<N_NODES / 4, 256, 0, stream>>>(rowp, ssrc, a_src1, a_dst1, h1, b1, out1);

  // --- layer 2 ---
  k_gemm2<<<(N_NODES + 255) / 256, 256, 0, stream>>>(out1, W2, att_src2, att_dst2, h2, a_src2, a_dst2);
  k_edge2<<<N_NODES / 4, 256, 0, stream>>>(rowp, ssrc, a_src2, a_dst2, h2, b2, out);
}

// Round 3
// 393.712 us; speedup vs baseline: 1.3381x; 1.2632x over previous
//
#include <hip/hip_runtime.h>
#include <math.h>

#define N_NODES   100000
#define N_EDGES   1600000
#define E_TOT     (N_EDGES + N_NODES)
#define N_FEAT    512
#define HEADS     8
#define F_HEAD    8
#define HIDDEN    64
#define N_CLASSES 40

#define BSHIFT    9
#define NBUCK     196                      // ceil(N_NODES / 512)
#define SC_NBLK   256
#define SC_CHUNK  ((E_TOT + SC_NBLK - 1) / SC_NBLK)   // 6641

typedef __attribute__((ext_vector_type(8))) short short8_t;
typedef __attribute__((ext_vector_type(4))) float f32x4;

// split fp32 -> bf16 hi + bf16 lo (both RNE)
__device__ inline void f2bf2(float x, unsigned short& h, unsigned short& l) {
  union { float f; unsigned u; } a; a.f = x;
  unsigned rh = a.u + 0x7FFFu + ((a.u >> 16) & 1u);
  unsigned short hv = (unsigned short)(rh >> 16);
  union { unsigned u; float f; } hf; hf.u = ((unsigned)hv) << 16;
  union { float f; unsigned u; } b; b.f = x - hf.f;
  unsigned rl = b.u + 0x7FFFu + ((b.u >> 16) & 1u);
  h = hv;
  l = (unsigned short)(rl >> 16);
}

// ============================ CSR build: two-level counting sort ============================
// Level 1: partition edges into 196 buckets of 512 dst nodes, per-block contiguous
// sub-ranges (coalesced-ish writes, no cross-XCD line sharing).
// Level 2: one block per bucket builds per-node CSR entirely in LDS.

__global__ __launch_bounds__(256) void k_bhist(const int* __restrict__ ei,
                                               int* __restrict__ gh) {
  __shared__ int h[NBUCK];
  int b = blockIdx.x, t = threadIdx.x;
  for (int i = t; i < NBUCK; i += 256) h[i] = 0;
  __syncthreads();
  int e0 = b * SC_CHUNK;
  int e1 = e0 + SC_CHUNK; if (e1 > E_TOT) e1 = E_TOT;
  for (int e = e0 + t; e < e1; e += 256) {
    int dst = (e < N_EDGES) ? ei[N_EDGES + e] : (e - N_EDGES);
    atomicAdd(&h[dst >> BSHIFT], 1);
  }
  __syncthreads();
  for (int i = t; i < NBUCK; i += 256) gh[b * 256 + i] = h[i];   // [block][bucket]
}

__global__ __launch_bounds__(256) void k_bscan(int* __restrict__ gh,
                                               int* __restrict__ bbase) {
  __shared__ int tot[256];
  __shared__ int red[256];
  int k = threadIdx.x;
  int s = 0;
  if (k < NBUCK) {
#pragma unroll 4
    for (int b = 0; b < SC_NBLK; ++b) s += gh[b * 256 + k];   // coalesced per iter
  }
  tot[k] = s;
  red[k] = s;
  __syncthreads();
  for (int off = 1; off < 256; off <<= 1) {
    int add = (k >= off) ? red[k - off] : 0;
    __syncthreads();
    red[k] += add;
    __syncthreads();
  }
  int excl = red[k] - tot[k];
  bbase[k] = excl;                       // for k >= NBUCK this equals E_TOT
  if (k == 255) bbase[256] = red[255];
  if (k < NBUCK) {
    int off = excl;
#pragma unroll 4
    for (int b = 0; b < SC_NBLK; ++b) {
      int c = gh[b * 256 + k];
      gh[b * 256 + k] = off;             // running global offset for (block b, bucket k)
      off += c;
    }
  }
}

__global__ __launch_bounds__(256) void k_bscatter(const int* __restrict__ ei,
                                                  const int* __restrict__ gh,
                                                  unsigned* __restrict__ ebuf) {
  __shared__ int offs[256];
  __shared__ int cnt[256];
  int b = blockIdx.x, t = threadIdx.x;
  offs[t] = gh[b * 256 + t];
  cnt[t] = 0;
  __syncthreads();
  int e0 = b * SC_CHUNK;
  int e1 = e0 + SC_CHUNK; if (e1 > E_TOT) e1 = E_TOT;
  for (int e = e0 + t; e < e1; e += 256) {
    int src, dst;
    if (e < N_EDGES) { src = ei[e]; dst = ei[N_EDGES + e]; }
    else             { src = e - N_EDGES; dst = src; }
    int k = dst >> BSHIFT;
    int r = atomicAdd(&cnt[k], 1);
    ebuf[offs[k] + r] = (unsigned)src | ((unsigned)(dst & 511) << 17);
  }
}

__global__ __launch_bounds__(256) void k_fine(const unsigned* __restrict__ ebuf,
                                              const int* __restrict__ bbase,
                                              int* __restrict__ rowp,
                                              int* __restrict__ ssrc) {
  __shared__ int cnt[512];
  __shared__ int red[256];
  __shared__ int cur[512];
  int k = blockIdx.x, t = threadIdx.x;
  int base = bbase[k], end = bbase[k + 1];
  cnt[t] = 0; cnt[t + 256] = 0;
  __syncthreads();
  for (int i = base + t; i < end; i += 256) atomicAdd(&cnt[ebuf[i] >> 17], 1);
  __syncthreads();
  int c0 = cnt[2 * t], c1 = cnt[2 * t + 1];
  int s = c0 + c1;
  red[t] = s;
  __syncthreads();
  for (int off = 1; off < 256; off <<= 1) {
    int add = (t >= off) ? red[t - off] : 0;
    __syncthreads();
    red[t] += add;
    __syncthreads();
  }
  int excl = red[t] - s;
  int p0 = base + excl;
  int p1 = p0 + c0;
  cur[2 * t] = p0; cur[2 * t + 1] = p1;
  int node = (k << BSHIFT) + 2 * t;
  if (node < N_NODES)     rowp[node]     = p0;
  if (node + 1 < N_NODES) rowp[node + 1] = p1;
  if (k == NBUCK - 1 && t == 0) rowp[N_NODES] = E_TOT;
  __syncthreads();
  for (int i = base + t; i < end; i += 256) {
    unsigned p = ebuf[i];
    int pos = atomicAdd(&cur[p >> 17], 1);
    ssrc[pos] = (int)(p & 0x1FFFFu);
  }
}

// ============================ W1 -> fragment-ordered bf16 hi/lo ============================

__global__ void k_w1frag(const float* __restrict__ W1, short* __restrict__ w1fh,
                         short* __restrict__ w1fl) {
  int idx = blockIdx.x * blockDim.x + threadIdx.x;
  if (idx >= N_FEAT * HIDDEN) return;
  int e    = idx & 7;
  int lane = (idx >> 3) & 63;
  int ct   = (idx >> 9) & 3;
  int ks   = idx >> 11;
  int col = ct * 16 + (lane & 15);
  int k   = ks * 32 + (lane >> 4) * 8 + e;
  unsigned short h, l;
  f2bf2(W1[k * HIDDEN + col], h, l);
  w1fh[idx] = (short)h;
  w1fl[idx] = (short)l;
}

// ============================ Layer 1 GEMM: h1 = x @ W1 (split-bf16 MFMA) ============================

#define G1_BM 128
#define G1_BK 64

__global__ __launch_bounds__(256) void k_gemm1(const float* __restrict__ x,
                                               const short* __restrict__ w1fh,
                                               const short* __restrict__ w1fl,
                                               float* __restrict__ h1) {
  __shared__ __align__(16) short Ah[G1_BM * G1_BK];   // 16 KB
  __shared__ __align__(16) short Al[G1_BM * G1_BK];   // 16 KB
  int t = threadIdx.x;
  int n0 = blockIdx.x * G1_BM;
  int w = t >> 6, l = t & 63;

  f32x4 acc[2][4];
#pragma unroll
  for (int i = 0; i < 2; ++i)
#pragma unroll
    for (int j = 0; j < 4; ++j) acc[i][j] = (f32x4){0.f, 0.f, 0.f, 0.f};

  for (int c = 0; c < N_FEAT / G1_BK; ++c) {
    if (c) __syncthreads();
#pragma unroll
    for (int i = 0; i < 4; ++i) {
      int s = i * 256 + t;
      int rt = s >> 7, ks = (s >> 6) & 1, ln = s & 63;
      int row = rt * 16 + (ln & 15);
      int kc = ks * 4 + (ln >> 4);
      int node = n0 + row;
      float v[8];
      if (node < N_NODES) {
        const float4* p = (const float4*)(x + (size_t)node * N_FEAT + c * G1_BK + kc * 8);
        float4 v0 = p[0], v1 = p[1];
        v[0] = v0.x; v[1] = v0.y; v[2] = v0.z; v[3] = v0.w;
        v[4] = v1.x; v[5] = v1.y; v[6] = v1.z; v[7] = v1.w;
      } else {
#pragma unroll
        for (int e = 0; e < 8; ++e) v[e] = 0.f;
      }
      short8_t hi, lo;
#pragma unroll
      for (int e = 0; e < 8; ++e) {
        unsigned short hh, ll;
        f2bf2(v[e], hh, ll);
        hi[e] = (short)hh;
        lo[e] = (short)ll;
      }
      *(short8_t*)&Ah[s * 8] = hi;
      *(short8_t*)&Al[s * 8] = lo;
    }
    __syncthreads();
#pragma unroll
    for (int ks2 = 0; ks2 < 2; ++ks2) {
      int gks = c * 2 + ks2;
      short8_t bh[4], bl[4];
#pragma unroll
      for (int ct = 0; ct < 4; ++ct) {
        bh[ct] = *(const short8_t*)(w1fh + ((size_t)(gks * 4 + ct) * 64 + l) * 8);
        bl[ct] = *(const short8_t*)(w1fl + ((size_t)(gks * 4 + ct) * 64 + l) * 8);
      }
#pragma unroll
      for (int rtl = 0; rtl < 2; ++rtl) {
        int rt = w * 2 + rtl;
        short8_t ah = *(const short8_t*)&Ah[(rt * 128 + ks2 * 64 + l) * 8];
        short8_t al = *(const short8_t*)&Al[(rt * 128 + ks2 * 64 + l) * 8];
#pragma unroll
        for (int ct = 0; ct < 4; ++ct) {
          acc[rtl][ct] = __builtin_amdgcn_mfma_f32_16x16x32_bf16(ah, bh[ct], acc[rtl][ct], 0, 0, 0);
          acc[rtl][ct] = __builtin_amdgcn_mfma_f32_16x16x32_bf16(ah, bl[ct], acc[rtl][ct], 0, 0, 0);
          acc[rtl][ct] = __builtin_amdgcn_mfma_f32_16x16x32_bf16(al, bh[ct], acc[rtl][ct], 0, 0, 0);
        }
      }
    }
  }
#pragma unroll
  for (int rtl = 0; rtl < 2; ++rtl) {
    int rbase = n0 + (w * 2 + rtl) * 16 + (l >> 4) * 4;
    int col0 = l & 15;
#pragma unroll
    for (int ct = 0; ct < 4; ++ct) {
      int col = ct * 16 + col0;
#pragma unroll
      for (int r = 0; r < 4; ++r) {
        int node = rbase + r;
        if (node < N_NODES) h1[(size_t)node * HIDDEN + col] = acc[rtl][ct][r];
      }
    }
  }
}

// ============================ layer-1 attention coefficients ============================

__global__ void k_att1(const float* __restrict__ h1, const float* __restrict__ att_src,
                       const float* __restrict__ att_dst, float* __restrict__ a_src,
                       float* __restrict__ a_dst) {
  int i = blockIdx.x * blockDim.x + threadIdx.x;   // i = node*8 + head
  if (i >= N_NODES * HEADS) return;
  int h = i & 7;
  const float4* hp = (const float4*)(h1 + (size_t)i * F_HEAD);
  float4 v0 = hp[0], v1 = hp[1];
  const float4* sp = (const float4*)(att_src + h * F_HEAD);
  const float4* dp = (const float4*)(att_dst + h * F_HEAD);
  float4 s0 = sp[0], s1 = sp[1], d0 = dp[0], d1 = dp[1];
  float as = v0.x * s0.x + v0.y * s0.y + v0.z * s0.z + v0.w * s0.w +
             v1.x * s1.x + v1.y * s1.y + v1.z * s1.z + v1.w * s1.w;
  float ad = v0.x * d0.x + v0.y * d0.y + v0.z * d0.z + v0.w * d0.w +
             v1.x * d1.x + v1.y * d1.y + v1.z * d1.z + v1.w * d1.w;
  a_src[i] = as;
  a_dst[i] = ad;
}

// ============================ layer-1 edge softmax + aggregate ============================

__global__ __launch_bounds__(256) void k_edge1(const int* __restrict__ rowp,
                                               const int* __restrict__ ssrc,
                                               const float* __restrict__ a_src,
                                               const float* __restrict__ a_dst,
                                               const float* __restrict__ h1,
                                               const float* __restrict__ b1,
                                               float* __restrict__ out1) {
  __shared__ float exs[4][64 * 9];
  __shared__ int   srcs[4][64];
  __shared__ int   mdeg;
  int t = threadIdx.x;
  int wv = t >> 6, lane = t & 63;
  int node = blockIdx.x * 4 + wv;
  int s0 = rowp[node];
  int s1 = rowp[node + 1];
  int deg = s1 - s0;
  if (t == 0) mdeg = 0;
  __syncthreads();
  if (lane == 0) atomicMax(&mdeg, deg);
  __syncthreads();
  int nchunks = (mdeg + 63) >> 6;

  float ad[8];
  {
    float4 d0 = *(const float4*)(a_dst + (size_t)node * 8);
    float4 d1 = *(const float4*)(a_dst + (size_t)node * 8 + 4);
    ad[0] = d0.x; ad[1] = d0.y; ad[2] = d0.z; ad[3] = d0.w;
    ad[4] = d1.x; ad[5] = d1.y; ad[6] = d1.z; ad[7] = d1.w;
  }
  float accv = 0.f, dsum = 0.f;
  int hof = lane >> 3;

  for (int c = 0; c < nchunks; ++c) {
    int base = s0 + (c << 6);
    int cn = s1 - base;
    cn = cn < 0 ? 0 : (cn > 64 ? 64 : cn);
    float ex[8];
    int sid = 0;
    if (lane < cn) {
      sid = ssrc[base + lane];
      float4 A0 = *(const float4*)(a_src + (size_t)sid * 8);
      float4 A1 = *(const float4*)(a_src + (size_t)sid * 8 + 4);
      float ea[8] = {A0.x + ad[0], A0.y + ad[1], A0.z + ad[2], A0.w + ad[3],
                     A1.x + ad[4], A1.y + ad[5], A1.z + ad[6], A1.w + ad[7]};
#pragma unroll
      for (int h = 0; h < 8; ++h) {
        float e = ea[h];
        e = e > 0.f ? e : 0.2f * e;
        ex[h] = expf(e);
      }
    } else {
#pragma unroll
      for (int h = 0; h < 8; ++h) ex[h] = 0.f;
    }
    __syncthreads();
    srcs[wv][lane] = sid;
#pragma unroll
    for (int h = 0; h < 8; ++h) exs[wv][lane * 9 + h] = ex[h];
    __syncthreads();
    for (int j = 0; j < cn; ++j) {
      float e = exs[wv][j * 9 + hof];
      int sj = srcs[wv][j];
      float hv = h1[(size_t)sj * HIDDEN + lane];
      accv = fmaf(e, hv, accv);
      dsum += e;
    }
  }
  float o = accv / (dsum + 1e-16f);
  o += b1[lane];
  o = o > 0.f ? o : expm1f(o);
  out1[(size_t)node * HIDDEN + lane] = o;
}

// ============================ Layer 2 GEMM + attention coeffs ============================

__global__ __launch_bounds__(256) void k_gemm2(const float* __restrict__ out1,
                                               const float* __restrict__ W2,
                                               const float* __restrict__ att_src2,
                                               const float* __restrict__ att_dst2,
                                               float* __restrict__ h2,
                                               float* __restrict__ a_src2,
                                               float* __restrict__ a_dst2) {
  __shared__ __align__(16) float w2s[HIDDEN * N_CLASSES];
  __shared__ float as2[N_CLASSES], ad2[N_CLASSES];
  int t = threadIdx.x;
  for (int i = t; i < HIDDEN * N_CLASSES; i += 256) w2s[i] = W2[i];
  if (t < N_CLASSES) { as2[t] = att_src2[t]; ad2[t] = att_dst2[t]; }
  __syncthreads();
  int node = blockIdx.x * 256 + t;
  if (node >= N_NODES) return;
  const float4* rp = (const float4*)(out1 + (size_t)node * HIDDEN);
  float acc[N_CLASSES];
#pragma unroll
  for (int c = 0; c < N_CLASSES; ++c) acc[c] = 0.f;
  for (int k4 = 0; k4 < 16; ++k4) {
    float4 rv = rp[k4];
#pragma unroll
    for (int kk = 0; kk < 4; ++kk) {
      float r = (kk == 0) ? rv.x : (kk == 1) ? rv.y : (kk == 2) ? rv.z : rv.w;
      const float* wrow = &w2s[(k4 * 4 + kk) * N_CLASSES];
#pragma unroll
      for (int c4 = 0; c4 < 10; ++c4) {
        float4 wvv = *(const float4*)(wrow + c4 * 4);
        acc[c4 * 4 + 0] = fmaf(r, wvv.x, acc[c4 * 4 + 0]);
        acc[c4 * 4 + 1] = fmaf(r, wvv.y, acc[c4 * 4 + 1]);
        acc[c4 * 4 + 2] = fmaf(r, wvv.z, acc[c4 * 4 + 2]);
        acc[c4 * 4 + 3] = fmaf(r, wvv.w, acc[c4 * 4 + 3]);
      }
    }
  }
  float as = 0.f, ad = 0.f;
#pragma unroll
  for (int c = 0; c < N_CLASSES; ++c) {
    as = fmaf(acc[c], as2[c], as);
    ad = fmaf(acc[c], ad2[c], ad);
  }
  float* hp = h2 + (size_t)node * N_CLASSES;
#pragma unroll
  for (int c4 = 0; c4 < 10; ++c4)
    *(float4*)(hp + c4 * 4) =
        make_float4(acc[c4 * 4], acc[c4 * 4 + 1], acc[c4 * 4 + 2], acc[c4 * 4 + 3]);
  a_src2[node] = as;
  a_dst2[node] = ad;
}

// ============================ layer-2 edge softmax + aggregate ============================

__global__ __launch_bounds__(256) void k_edge2(const int* __restrict__ rowp,
                                               const int* __restrict__ ssrc,
                                               const float* __restrict__ a_src,
                                               const float* __restrict__ a_dst,
                                               const float* __restrict__ h2,
                                               const float* __restrict__ b2,
                                               float* __restrict__ out) {
  __shared__ float exs[4][64];
  __shared__ int   srcs[4][64];
  __shared__ int   mdeg;
  int t = threadIdx.x;
  int wv = t >> 6, lane = t & 63;
  int node = blockIdx.x * 4 + wv;
  int s0 = rowp[node];
  int s1 = rowp[node + 1];
  int deg = s1 - s0;
  if (t == 0) mdeg = 0;
  __syncthreads();
  if (lane == 0) atomicMax(&mdeg, deg);
  __syncthreads();
  int nchunks = (mdeg + 63) >> 6;

  float adv = a_dst[node];
  float accv = 0.f, dsum = 0.f;

  for (int c = 0; c < nchunks; ++c) {
    int base = s0 + (c << 6);
    int cn = s1 - base;
    cn = cn < 0 ? 0 : (cn > 64 ? 64 : cn);
    float exv = 0.f;
    int sid = 0;
    if (lane < cn) {
      sid = ssrc[base + lane];
      float e = a_src[sid] + adv;
      e = e > 0.f ? e : 0.2f * e;
      exv = expf(e);
    }
    __syncthreads();
    srcs[wv][lane] = sid;
    exs[wv][lane] = exv;
    __syncthreads();
    for (int j = 0; j < cn; ++j) {
      float e = exs[wv][j];
      dsum += e;
      if (lane < N_CLASSES) {
        int sj = srcs[wv][j];
        accv = fmaf(e, h2[(size_t)sj * N_CLASSES + lane], accv);
      }
    }
  }
  if (lane < N_CLASSES)
    out[(size_t)node * N_CLASSES + lane] = accv / (dsum + 1e-16f) + b2[lane];
}

// ============================ launch ============================

extern "C" void kernel_launch(void* const* d_in, const int* in_sizes, int n_in,
                              void* d_out, int out_size, void* d_ws, size_t ws_size,
                              hipStream_t stream) {
  const float* x        = (const float*)d_in[0];
  const int*   ei       = (const int*)d_in[1];
  const float* W1       = (const float*)d_in[2];
  const float* att_src1 = (const float*)d_in[3];
  const float* att_dst1 = (const float*)d_in[4];
  const float* b1       = (const float*)d_in[5];
  const float* W2       = (const float*)d_in[6];
  const float* att_src2 = (const float*)d_in[7];
  const float* att_dst2 = (const float*)d_in[8];
  const float* b2       = (const float*)d_in[9];
  float* out = (float*)d_out;

  char* w = (char*)d_ws;
  float* h1     = (float*)(w);                    // 25,600,000 B (reused as h2)
  float* out1   = (float*)(w + 25600000);         // 25,600,000 B
  float* a_src1 = (float*)(w + 51200000);         //  3,200,000 B
  float* a_dst1 = (float*)(w + 54400000);         //  3,200,000 B
  int*   rowp   = (int*)(w + 57600000);           //    400,128 B
  int*   ssrc   = (int*)(w + 58000128);           //  6,800,000 B
  short* w1fh   = (short*)(w + 64800128);         //     65,536 B
  short* w1fl   = (short*)(w + 64865664);         //     65,536 B
  // build-time aliases (dead before h1/out1 are written):
  unsigned* ebuf = (unsigned*)(w);                //  6,800,000 B, aliases h1
  int*   gh     = (int*)(w + 25600000);           //    262,144 B, aliases out1
  int*   bbase  = (int*)(w + 25862144);           //      1,028 B, aliases out1

  float* h2     = h1;
  float* a_src2 = a_src1;
  float* a_dst2 = a_src1 + N_NODES;

  // --- W1 fragment precompute + CSR build ---
  k_w1frag<<<(N_FEAT * HIDDEN + 255) / 256, 256, 0, stream>>>(W1, w1fh, w1fl);
  k_bhist<<<SC_NBLK, 256, 0, stream>>>(ei, gh);
  k_bscan<<<1, 256, 0, stream>>>(gh, bbase);
  k_bscatter<<<SC_NBLK, 256, 0, stream>>>(ei, gh, ebuf);
  k_fine<<<NBUCK, 256, 0, stream>>>(ebuf, bbase, rowp, ssrc);

  // --- layer 1 ---
  k_gemm1<<<(N_NODES + G1_BM - 1) / G1_BM, 256, 0, stream>>>(x, w1fh, w1fl, h1);
  k_att1<<<(N_NODES * HEADS + 255) / 256, 256, 0, stream>>>(h1, att_src1, att_dst1, a_src1, a_dst1);
  k_edge1<<<N_NODES / 4, 256, 0, stream>>>(rowp, ssrc, a_src1, a_dst1, h1, b1, out1);

  // --- layer 2 ---
  k_gemm2<<<(N_NODES + 255) / 256, 256, 0, stream>>>(out1, W2, att_src2, att_dst2, h2, a_src2, a_dst2);
  k_edge2<<<N_NODES / 4, 256, 0, stream>>>(rowp, ssrc, a_src2, a_dst2, h2, b2, out);
}

// Round 4
// 375.100 us; speedup vs baseline: 1.4045x; 1.0496x over previous
//
#include <hip/hip_runtime.h>
#include <math.h>

#define N_NODES   100000
#define N_EDGES   1600000
#define E_TOT     (N_EDGES + N_NODES)
#define N_FEAT    512
#define HEADS     8
#define F_HEAD    8
#define HIDDEN    64
#define N_CLASSES 40

#define BSHIFT    9
#define NBUCK     196                      // ceil(N_NODES / 512)
#define SC_NBLK   256
#define SC_CHUNK  ((E_TOT + SC_NBLK - 1) / SC_NBLK)   // 6641

typedef __attribute__((ext_vector_type(8))) short short8_t;
typedef __attribute__((ext_vector_type(4))) float f32x4;

// split fp32 -> bf16 hi + bf16 lo (both RNE)
__device__ inline void f2bf2(float x, unsigned short& h, unsigned short& l) {
  union { float f; unsigned u; } a; a.f = x;
  unsigned rh = a.u + 0x7FFFu + ((a.u >> 16) & 1u);
  unsigned short hv = (unsigned short)(rh >> 16);
  union { unsigned u; float f; } hf; hf.u = ((unsigned)hv) << 16;
  union { float f; unsigned u; } b; b.f = x - hf.f;
  unsigned rl = b.u + 0x7FFFu + ((b.u >> 16) & 1u);
  h = hv;
  l = (unsigned short)(rl >> 16);
}

__device__ inline void cvt8(const float4& v0, const float4& v1, short8_t& hi, short8_t& lo) {
  float v[8] = {v0.x, v0.y, v0.z, v0.w, v1.x, v1.y, v1.z, v1.w};
#pragma unroll
  for (int e = 0; e < 8; ++e) {
    unsigned short hh, ll;
    f2bf2(v[e], hh, ll);
    hi[e] = (short)hh;
    lo[e] = (short)ll;
  }
}

// ============================ CSR build: two-level counting sort ============================

__global__ __launch_bounds__(256) void k_bhist(const int* __restrict__ ei,
                                               int* __restrict__ gh) {
  __shared__ int h[NBUCK];
  int b = blockIdx.x, t = threadIdx.x;
  for (int i = t; i < NBUCK; i += 256) h[i] = 0;
  __syncthreads();
  int e0 = b * SC_CHUNK;
  int e1 = e0 + SC_CHUNK; if (e1 > E_TOT) e1 = E_TOT;
  for (int e = e0 + t; e < e1; e += 256) {
    int dst = (e < N_EDGES) ? ei[N_EDGES + e] : (e - N_EDGES);
    atomicAdd(&h[dst >> BSHIFT], 1);
  }
  __syncthreads();
  for (int i = t; i < NBUCK; i += 256) gh[b * 256 + i] = h[i];   // [block][bucket]
}

__global__ __launch_bounds__(256) void k_bscan(int* __restrict__ gh,
                                               int* __restrict__ bbase) {
  __shared__ int tot[256];
  __shared__ int red[256];
  int k = threadIdx.x;
  int s = 0;
  if (k < NBUCK) {
#pragma unroll 4
    for (int b = 0; b < SC_NBLK; ++b) s += gh[b * 256 + k];
  }
  tot[k] = s;
  red[k] = s;
  __syncthreads();
  for (int off = 1; off < 256; off <<= 1) {
    int add = (k >= off) ? red[k - off] : 0;
    __syncthreads();
    red[k] += add;
    __syncthreads();
  }
  int excl = red[k] - tot[k];
  bbase[k] = excl;
  if (k == 255) bbase[256] = red[255];
  if (k < NBUCK) {
    int off = excl;
#pragma unroll 4
    for (int b = 0; b < SC_NBLK; ++b) {
      int c = gh[b * 256 + k];
      gh[b * 256 + k] = off;
      off += c;
    }
  }
}

__global__ __launch_bounds__(256) void k_bscatter(const int* __restrict__ ei,
                                                  const int* __restrict__ gh,
                                                  unsigned* __restrict__ ebuf) {
  __shared__ int offs[256];
  __shared__ int cnt[256];
  int b = blockIdx.x, t = threadIdx.x;
  offs[t] = gh[b * 256 + t];
  cnt[t] = 0;
  __syncthreads();
  int e0 = b * SC_CHUNK;
  int e1 = e0 + SC_CHUNK; if (e1 > E_TOT) e1 = E_TOT;
  for (int e = e0 + t; e < e1; e += 256) {
    int src, dst;
    if (e < N_EDGES) { src = ei[e]; dst = ei[N_EDGES + e]; }
    else             { src = e - N_EDGES; dst = src; }
    int k = dst >> BSHIFT;
    int r = atomicAdd(&cnt[k], 1);
    ebuf[offs[k] + r] = (unsigned)src | ((unsigned)(dst & 511) << 17);
  }
}

__global__ __launch_bounds__(256) void k_fine(const unsigned* __restrict__ ebuf,
                                              const int* __restrict__ bbase,
                                              int* __restrict__ rowp,
                                              int* __restrict__ ssrc) {
  __shared__ int cnt[512];
  __shared__ int red[256];
  __shared__ int cur[512];
  int k = blockIdx.x, t = threadIdx.x;
  int base = bbase[k], end = bbase[k + 1];
  cnt[t] = 0; cnt[t + 256] = 0;
  __syncthreads();
  for (int i = base + t; i < end; i += 256) atomicAdd(&cnt[ebuf[i] >> 17], 1);
  __syncthreads();
  int c0 = cnt[2 * t], c1 = cnt[2 * t + 1];
  int s = c0 + c1;
  red[t] = s;
  __syncthreads();
  for (int off = 1; off < 256; off <<= 1) {
    int add = (t >= off) ? red[t - off] : 0;
    __syncthreads();
    red[t] += add;
    __syncthreads();
  }
  int excl = red[t] - s;
  int p0 = base + excl;
  int p1 = p0 + c0;
  cur[2 * t] = p0; cur[2 * t + 1] = p1;
  int node = (k << BSHIFT) + 2 * t;
  if (node < N_NODES)     rowp[node]     = p0;
  if (node + 1 < N_NODES) rowp[node + 1] = p1;
  if (k == NBUCK - 1 && t == 0) rowp[N_NODES] = E_TOT;
  __syncthreads();
  for (int i = base + t; i < end; i += 256) {
    unsigned p = ebuf[i];
    int pos = atomicAdd(&cur[p >> 17], 1);
    ssrc[pos] = (int)(p & 0x1FFFFu);
  }
}

// ============================ W1 -> fragment-ordered bf16 hi/lo ============================

__global__ void k_w1frag(const float* __restrict__ W1, short* __restrict__ w1fh,
                         short* __restrict__ w1fl) {
  int idx = blockIdx.x * blockDim.x + threadIdx.x;
  if (idx >= N_FEAT * HIDDEN) return;
  int e    = idx & 7;
  int lane = (idx >> 3) & 63;
  int ct   = (idx >> 9) & 3;
  int ks   = idx >> 11;
  int col = ct * 16 + (lane & 15);
  int k   = ks * 32 + (lane >> 4) * 8 + e;
  unsigned short h, l;
  f2bf2(W1[k * HIDDEN + col], h, l);
  w1fh[idx] = (short)h;
  w1fl[idx] = (short)l;
}

// ============================ Layer 1 GEMM: h1 = x @ W1 (split-bf16 MFMA) ============================
// LDS-free, barrier-free: each wave owns 32 rows x 64 cols; A fragments loaded
// per-lane directly from x (8 contiguous fp32 = 2 float4), converted in-register.
// B fragments lane-contiguous dwordx4 from fragment-ordered w1fh/w1fl (L2-resident).

__global__ __launch_bounds__(256) void k_gemm1(const float* __restrict__ x,
                                               const short* __restrict__ w1fh,
                                               const short* __restrict__ w1fl,
                                               float* __restrict__ h1) {
  int t = threadIdx.x;
  int w = t >> 6, l = t & 63;
  int n0 = blockIdx.x * 128 + w * 32;       // wave's first row
  int r0 = l & 15;
  int kq8 = (l >> 4) * 8;                    // k offset within 32-chunk
  const float* pA = x + (size_t)(n0 + r0) * N_FEAT + kq8;
  const float* pB = x + (size_t)(n0 + 16 + r0) * N_FEAT + kq8;
  bool vA = (n0 + r0) < N_NODES;
  bool vB = (n0 + 16 + r0) < N_NODES;

  f32x4 acc[2][4];
#pragma unroll
  for (int i = 0; i < 2; ++i)
#pragma unroll
    for (int j = 0; j < 4; ++j) acc[i][j] = (f32x4){0.f, 0.f, 0.f, 0.f};

#pragma unroll 2
  for (int gks = 0; gks < 16; ++gks) {
    int boff = (gks * 2048) + l * 8;         // (gks*4+ct)*64*8 + l*8, ct stride 512
    short8_t bh[4], bl[4];
#pragma unroll
    for (int ct = 0; ct < 4; ++ct) {
      bh[ct] = *(const short8_t*)(w1fh + boff + ct * 512);
      bl[ct] = *(const short8_t*)(w1fl + boff + ct * 512);
    }
    float4 a0 = make_float4(0.f, 0.f, 0.f, 0.f), a1 = a0, c0 = a0, c1 = a0;
    if (vA) {
      const float4* p = (const float4*)(pA + gks * 32);
      a0 = p[0]; a1 = p[1];
    }
    if (vB) {
      const float4* p = (const float4*)(pB + gks * 32);
      c0 = p[0]; c1 = p[1];
    }
    short8_t ahA, alA, ahB, alB;
    cvt8(a0, a1, ahA, alA);
    cvt8(c0, c1, ahB, alB);
#pragma unroll
    for (int ct = 0; ct < 4; ++ct) {
      acc[0][ct] = __builtin_amdgcn_mfma_f32_16x16x32_bf16(ahA, bh[ct], acc[0][ct], 0, 0, 0);
      acc[0][ct] = __builtin_amdgcn_mfma_f32_16x16x32_bf16(ahA, bl[ct], acc[0][ct], 0, 0, 0);
      acc[0][ct] = __builtin_amdgcn_mfma_f32_16x16x32_bf16(alA, bh[ct], acc[0][ct], 0, 0, 0);
      acc[1][ct] = __builtin_amdgcn_mfma_f32_16x16x32_bf16(ahB, bh[ct], acc[1][ct], 0, 0, 0);
      acc[1][ct] = __builtin_amdgcn_mfma_f32_16x16x32_bf16(ahB, bl[ct], acc[1][ct], 0, 0, 0);
      acc[1][ct] = __builtin_amdgcn_mfma_f32_16x16x32_bf16(alB, bh[ct], acc[1][ct], 0, 0, 0);
    }
  }
  // epilogue: C/D layout col=lane&15, row=(lane>>4)*4+reg
#pragma unroll
  for (int rtl = 0; rtl < 2; ++rtl) {
    int rbase = n0 + rtl * 16 + (l >> 4) * 4;
    int col0 = l & 15;
#pragma unroll
    for (int ct = 0; ct < 4; ++ct) {
      int col = ct * 16 + col0;
#pragma unroll
      for (int r = 0; r < 4; ++r) {
        int node = rbase + r;
        if (node < N_NODES) h1[(size_t)node * HIDDEN + col] = acc[rtl][ct][r];
      }
    }
  }
}

// ============================ layer-1 attention coefficients ============================

__global__ void k_att1(const float* __restrict__ h1, const float* __restrict__ att_src,
                       const float* __restrict__ att_dst, float* __restrict__ a_src,
                       float* __restrict__ a_dst) {
  int i = blockIdx.x * blockDim.x + threadIdx.x;   // i = node*8 + head
  if (i >= N_NODES * HEADS) return;
  int h = i & 7;
  const float4* hp = (const float4*)(h1 + (size_t)i * F_HEAD);
  float4 v0 = hp[0], v1 = hp[1];
  const float4* sp = (const float4*)(att_src + h * F_HEAD);
  const float4* dp = (const float4*)(att_dst + h * F_HEAD);
  float4 s0 = sp[0], s1 = sp[1], d0 = dp[0], d1 = dp[1];
  float as = v0.x * s0.x + v0.y * s0.y + v0.z * s0.z + v0.w * s0.w +
             v1.x * s1.x + v1.y * s1.y + v1.z * s1.z + v1.w * s1.w;
  float ad = v0.x * d0.x + v0.y * d0.y + v0.z * d0.z + v0.w * d0.w +
             v1.x * d1.x + v1.y * d1.y + v1.z * d1.z + v1.w * d1.w;
  a_src[i] = as;
  a_dst[i] = ad;
}

// ============================ layer-1 edge softmax + aggregate ============================

__global__ __launch_bounds__(256) void k_edge1(const int* __restrict__ rowp,
                                               const int* __restrict__ ssrc,
                                               const float* __restrict__ a_src,
                                               const float* __restrict__ a_dst,
                                               const float* __restrict__ h1,
                                               const float* __restrict__ b1,
                                               float* __restrict__ out1) {
  __shared__ float exs[4][64 * 9];
  __shared__ int   srcs[4][64];
  __shared__ int   mdeg;
  int t = threadIdx.x;
  int wv = t >> 6, lane = t & 63;
  int node = blockIdx.x * 4 + wv;
  int s0 = rowp[node];
  int s1 = rowp[node + 1];
  int deg = s1 - s0;
  if (t == 0) mdeg = 0;
  __syncthreads();
  if (lane == 0) atomicMax(&mdeg, deg);
  __syncthreads();
  int nchunks = (mdeg + 63) >> 6;

  float ad[8];
  {
    float4 d0 = *(const float4*)(a_dst + (size_t)node * 8);
    float4 d1 = *(const float4*)(a_dst + (size_t)node * 8 + 4);
    ad[0] = d0.x; ad[1] = d0.y; ad[2] = d0.z; ad[3] = d0.w;
    ad[4] = d1.x; ad[5] = d1.y; ad[6] = d1.z; ad[7] = d1.w;
  }
  float accv = 0.f, dsum = 0.f;
  int hof = lane >> 3;

  for (int c = 0; c < nchunks; ++c) {
    int base = s0 + (c << 6);
    int cn = s1 - base;
    cn = cn < 0 ? 0 : (cn > 64 ? 64 : cn);
    float ex[8];
    int sid = 0;
    if (lane < cn) {
      sid = ssrc[base + lane];
      float4 A0 = *(const float4*)(a_src + (size_t)sid * 8);
      float4 A1 = *(const float4*)(a_src + (size_t)sid * 8 + 4);
      float ea[8] = {A0.x + ad[0], A0.y + ad[1], A0.z + ad[2], A0.w + ad[3],
                     A1.x + ad[4], A1.y + ad[5], A1.z + ad[6], A1.w + ad[7]};
#pragma unroll
      for (int h = 0; h < 8; ++h) {
        float e = ea[h];
        e = e > 0.f ? e : 0.2f * e;
        ex[h] = expf(e);
      }
    } else {
#pragma unroll
      for (int h = 0; h < 8; ++h) ex[h] = 0.f;
    }
    __syncthreads();
    srcs[wv][lane] = sid;
#pragma unroll
    for (int h = 0; h < 8; ++h) exs[wv][lane * 9 + h] = ex[h];
    __syncthreads();
    for (int j = 0; j < cn; ++j) {
      float e = exs[wv][j * 9 + hof];
      int sj = srcs[wv][j];
      float hv = h1[(size_t)sj * HIDDEN + lane];
      accv = fmaf(e, hv, accv);
      dsum += e;
    }
  }
  float o = accv / (dsum + 1e-16f);
  o += b1[lane];
  o = o > 0.f ? o : expm1f(o);
  out1[(size_t)node * HIDDEN + lane] = o;
}

// ============================ Layer 2 GEMM + attention coeffs ============================

__global__ __launch_bounds__(256) void k_gemm2(const float* __restrict__ out1,
                                               const float* __restrict__ W2,
                                               const float* __restrict__ att_src2,
                                               const float* __restrict__ att_dst2,
                                               float* __restrict__ h2,
                                               float* __restrict__ a_src2,
                                               float* __restrict__ a_dst2) {
  __shared__ __align__(16) float w2s[HIDDEN * N_CLASSES];
  __shared__ float as2[N_CLASSES], ad2[N_CLASSES];
  int t = threadIdx.x;
  for (int i = t; i < HIDDEN * N_CLASSES; i += 256) w2s[i] = W2[i];
  if (t < N_CLASSES) { as2[t] = att_src2[t]; ad2[t] = att_dst2[t]; }
  __syncthreads();
  int node = blockIdx.x * 256 + t;
  if (node >= N_NODES) return;
  const float4* rp = (const float4*)(out1 + (size_t)node * HIDDEN);
  float acc[N_CLASSES];
#pragma unroll
  for (int c = 0; c < N_CLASSES; ++c) acc[c] = 0.f;
  for (int k4 = 0; k4 < 16; ++k4) {
    float4 rv = rp[k4];
#pragma unroll
    for (int kk = 0; kk < 4; ++kk) {
      float r = (kk == 0) ? rv.x : (kk == 1) ? rv.y : (kk == 2) ? rv.z : rv.w;
      const float* wrow = &w2s[(k4 * 4 + kk) * N_CLASSES];
#pragma unroll
      for (int c4 = 0; c4 < 10; ++c4) {
        float4 wvv = *(const float4*)(wrow + c4 * 4);
        acc[c4 * 4 + 0] = fmaf(r, wvv.x, acc[c4 * 4 + 0]);
        acc[c4 * 4 + 1] = fmaf(r, wvv.y, acc[c4 * 4 + 1]);
        acc[c4 * 4 + 2] = fmaf(r, wvv.z, acc[c4 * 4 + 2]);
        acc[c4 * 4 + 3] = fmaf(r, wvv.w, acc[c4 * 4 + 3]);
      }
    }
  }
  float as = 0.f, ad = 0.f;
#pragma unroll
  for (int c = 0; c < N_CLASSES; ++c) {
    as = fmaf(acc[c], as2[c], as);
    ad = fmaf(acc[c], ad2[c], ad);
  }
  float* hp = h2 + (size_t)node * N_CLASSES;
#pragma unroll
  for (int c4 = 0; c4 < 10; ++c4)
    *(float4*)(hp + c4 * 4) =
        make_float4(acc[c4 * 4], acc[c4 * 4 + 1], acc[c4 * 4 + 2], acc[c4 * 4 + 3]);
  a_src2[node] = as;
  a_dst2[node] = ad;
}

// ============================ layer-2 edge softmax + aggregate ============================

__global__ __launch_bounds__(256) void k_edge2(const int* __restrict__ rowp,
                                               const int* __restrict__ ssrc,
                                               const float* __restrict__ a_src,
                                               const float* __restrict__ a_dst,
                                               const float* __restrict__ h2,
                                               const float* __restrict__ b2,
                                               float* __restrict__ out) {
  __shared__ float exs[4][64];
  __shared__ int   srcs[4][64];
  __shared__ int   mdeg;
  int t = threadIdx.x;
  int wv = t >> 6, lane = t & 63;
  int node = blockIdx.x * 4 + wv;
  int s0 = rowp[node];
  int s1 = rowp[node + 1];
  int deg = s1 - s0;
  if (t == 0) mdeg = 0;
  __syncthreads();
  if (lane == 0) atomicMax(&mdeg, deg);
  __syncthreads();
  int nchunks = (mdeg + 63) >> 6;

  float adv = a_dst[node];
  float accv = 0.f, dsum = 0.f;

  for (int c = 0; c < nchunks; ++c) {
    int base = s0 + (c << 6);
    int cn = s1 - base;
    cn = cn < 0 ? 0 : (cn > 64 ? 64 : cn);
    float exv = 0.f;
    int sid = 0;
    if (lane < cn) {
      sid = ssrc[base + lane];
      float e = a_src[sid] + adv;
      e = e > 0.f ? e : 0.2f * e;
      exv = expf(e);
    }
    __syncthreads();
    srcs[wv][lane] = sid;
    exs[wv][lane] = exv;
    __syncthreads();
    for (int j = 0; j < cn; ++j) {
      float e = exs[wv][j];
      dsum += e;
      if (lane < N_CLASSES) {
        int sj = srcs[wv][j];
        accv = fmaf(e, h2[(size_t)sj * N_CLASSES + lane], accv);
      }
    }
  }
  if (lane < N_CLASSES)
    out[(size_t)node * N_CLASSES + lane] = accv / (dsum + 1e-16f) + b2[lane];
}

// ============================ launch ============================

extern "C" void kernel_launch(void* const* d_in, const int* in_sizes, int n_in,
                              void* d_out, int out_size, void* d_ws, size_t ws_size,
                              hipStream_t stream) {
  const float* x        = (const float*)d_in[0];
  const int*   ei       = (const int*)d_in[1];
  const float* W1       = (const float*)d_in[2];
  const float* att_src1 = (const float*)d_in[3];
  const float* att_dst1 = (const float*)d_in[4];
  const float* b1       = (const float*)d_in[5];
  const float* W2       = (const float*)d_in[6];
  const float* att_src2 = (const float*)d_in[7];
  const float* att_dst2 = (const float*)d_in[8];
  const float* b2       = (const float*)d_in[9];
  float* out = (float*)d_out;

  char* w = (char*)d_ws;
  float* h1     = (float*)(w);                    // 25,600,000 B (reused as h2)
  float* out1   = (float*)(w + 25600000);         // 25,600,000 B
  float* a_src1 = (float*)(w + 51200000);         //  3,200,000 B
  float* a_dst1 = (float*)(w + 54400000);         //  3,200,000 B
  int*   rowp   = (int*)(w + 57600000);           //    400,128 B
  int*   ssrc   = (int*)(w + 58000128);           //  6,800,000 B
  short* w1fh   = (short*)(w + 64800128);         //     65,536 B
  short* w1fl   = (short*)(w + 64865664);         //     65,536 B
  // build-time aliases (dead before h1/out1 are written):
  unsigned* ebuf = (unsigned*)(w);                //  6,800,000 B, aliases h1
  int*   gh     = (int*)(w + 25600000);           //    262,144 B, aliases out1
  int*   bbase  = (int*)(w + 25862144);           //      1,028 B, aliases out1

  float* h2     = h1;
  float* a_src2 = a_src1;
  float* a_dst2 = a_src1 + N_NODES;

  // --- W1 fragment precompute + CSR build ---
  k_w1frag<<<(N_FEAT * HIDDEN + 255) / 256, 256, 0, stream>>>(W1, w1fh, w1fl);
  k_bhist<<<SC_NBLK, 256, 0, stream>>>(ei, gh);
  k_bscan<<<1, 256, 0, stream>>>(gh, bbase);
  k_bscatter<<<SC_NBLK, 256, 0, stream>>>(ei, gh, ebuf);
  k_fine<<<NBUCK, 256, 0, stream>>>(ebuf, bbase, rowp, ssrc);

  // --- layer 1 ---
  k_gemm1<<<(N_NODES + 127) / 128, 256, 0, stream>>>(x, w1fh, w1fl, h1);
  k_att1<<<(N_NODES * HEADS + 255) / 256, 256, 0, stream>>>(h1, att_src1, att_dst1, a_src1, a_dst1);
  k_edge1<<<N_NODES / 4, 256, 0, stream>>>(rowp, ssrc, a_src1, a_dst1, h1, b1, out1);

  // --- layer 2 ---
  k_gemm2<<<(N_NODES + 255) / 256, 256, 0, stream>>>(out1, W2, att_src2, att_dst2, h2, a_src2, a_dst2);
  k_edge2<<<N_NODES / 4, 256, 0, stream>>>(rowp, ssrc, a_src2, a_dst2, h2, b2, out);
}

// Round 5
// 362.504 us; speedup vs baseline: 1.4533x; 1.0347x over previous
//
#include <hip/hip_runtime.h>
#include <math.h>

#define N_NODES   100000
#define N_EDGES   1600000
#define E_TOT     (N_EDGES + N_NODES)
#define N_FEAT    512
#define HEADS     8
#define F_HEAD    8
#define HIDDEN    64
#define N_CLASSES 40

#define BSHIFT    9
#define NBUCK     196                      // ceil(N_NODES / 512)
#define SC_NBLK   256
#define SC_CHUNK  ((E_TOT + SC_NBLK - 1) / SC_NBLK)   // 6641

typedef __attribute__((ext_vector_type(8))) short short8_t;
typedef __attribute__((ext_vector_type(4))) float f32x4;

// split fp32 -> bf16 hi + bf16 lo (both RNE)
__device__ inline void f2bf2(float x, unsigned short& h, unsigned short& l) {
  union { float f; unsigned u; } a; a.f = x;
  unsigned rh = a.u + 0x7FFFu + ((a.u >> 16) & 1u);
  unsigned short hv = (unsigned short)(rh >> 16);
  union { unsigned u; float f; } hf; hf.u = ((unsigned)hv) << 16;
  union { float f; unsigned u; } b; b.f = x - hf.f;
  unsigned rl = b.u + 0x7FFFu + ((b.u >> 16) & 1u);
  h = hv;
  l = (unsigned short)(rl >> 16);
}

__device__ inline void cvt8(const float4& v0, const float4& v1, short8_t& hi, short8_t& lo) {
  float v[8] = {v0.x, v0.y, v0.z, v0.w, v1.x, v1.y, v1.z, v1.w};
#pragma unroll
  for (int e = 0; e < 8; ++e) {
    unsigned short hh, ll;
    f2bf2(v[e], hh, ll);
    hi[e] = (short)hh;
    lo[e] = (short)ll;
  }
}

// ============================ CSR build: two-level counting sort ============================
// ghT layout: [bucket][block] so per-bucket scans are parallel + coalesced.

__global__ __launch_bounds__(256) void k_bhist(const int* __restrict__ ei,
                                               int* __restrict__ ghT) {
  __shared__ int h[NBUCK];
  int b = blockIdx.x, t = threadIdx.x;
  for (int i = t; i < NBUCK; i += 256) h[i] = 0;
  __syncthreads();
  int e0 = b * SC_CHUNK;
  int e1 = e0 + SC_CHUNK; if (e1 > E_TOT) e1 = E_TOT;
  for (int e = e0 + t; e < e1; e += 256) {
    int dst = (e < N_EDGES) ? ei[N_EDGES + e] : (e - N_EDGES);
    atomicAdd(&h[dst >> BSHIFT], 1);
  }
  __syncthreads();
  for (int i = t; i < NBUCK; i += 256) ghT[i * SC_NBLK + b] = h[i];
}

// per-bucket: exclusive prefix over blocks (in place) + bucket total
__global__ __launch_bounds__(256) void k_scan1(int* __restrict__ ghT,
                                               int* __restrict__ btot) {
  __shared__ int red[256];
  int k = blockIdx.x, t = threadIdx.x;
  int v = ghT[k * SC_NBLK + t];
  red[t] = v;
  __syncthreads();
  for (int off = 1; off < 256; off <<= 1) {
    int add = (t >= off) ? red[t - off] : 0;
    __syncthreads();
    red[t] += add;
    __syncthreads();
  }
  ghT[k * SC_NBLK + t] = red[t] - v;     // exclusive intra-bucket prefix
  if (t == 255) btot[k] = red[255];
}

// tiny: exclusive scan over 196 bucket totals
__global__ __launch_bounds__(256) void k_scan2(const int* __restrict__ btot,
                                               int* __restrict__ bbase) {
  __shared__ int red[256];
  int t = threadIdx.x;
  int v = (t < NBUCK) ? btot[t] : 0;
  red[t] = v;
  __syncthreads();
  for (int off = 1; off < 256; off <<= 1) {
    int add = (t >= off) ? red[t - off] : 0;
    __syncthreads();
    red[t] += add;
    __syncthreads();
  }
  if (t < NBUCK) bbase[t] = red[t] - v;
  if (t == NBUCK - 1) bbase[NBUCK] = red[t];
}

__global__ __launch_bounds__(256) void k_bscatter(const int* __restrict__ ei,
                                                  const int* __restrict__ ghT,
                                                  const int* __restrict__ bbase,
                                                  unsigned* __restrict__ ebuf) {
  __shared__ int offs[256];
  __shared__ int cnt[256];
  int b = blockIdx.x, t = threadIdx.x;
  offs[t] = (t < NBUCK) ? (ghT[t * SC_NBLK + b] + bbase[t]) : 0;
  cnt[t] = 0;
  __syncthreads();
  int e0 = b * SC_CHUNK;
  int e1 = e0 + SC_CHUNK; if (e1 > E_TOT) e1 = E_TOT;
  for (int e = e0 + t; e < e1; e += 256) {
    int src, dst;
    if (e < N_EDGES) { src = ei[e]; dst = ei[N_EDGES + e]; }
    else             { src = e - N_EDGES; dst = src; }
    int k = dst >> BSHIFT;
    int r = atomicAdd(&cnt[k], 1);
    ebuf[offs[k] + r] = (unsigned)src | ((unsigned)(dst & 511) << 17);
  }
}

__global__ __launch_bounds__(256) void k_fine(const unsigned* __restrict__ ebuf,
                                              const int* __restrict__ bbase,
                                              int* __restrict__ rowp,
                                              int* __restrict__ ssrc) {
  __shared__ int cnt[512];
  __shared__ int red[256];
  __shared__ int cur[512];
  int k = blockIdx.x, t = threadIdx.x;
  int base = bbase[k], end = bbase[k + 1];
  cnt[t] = 0; cnt[t + 256] = 0;
  __syncthreads();
  for (int i = base + t; i < end; i += 256) atomicAdd(&cnt[ebuf[i] >> 17], 1);
  __syncthreads();
  int c0 = cnt[2 * t], c1 = cnt[2 * t + 1];
  int s = c0 + c1;
  red[t] = s;
  __syncthreads();
  for (int off = 1; off < 256; off <<= 1) {
    int add = (t >= off) ? red[t - off] : 0;
    __syncthreads();
    red[t] += add;
    __syncthreads();
  }
  int excl = red[t] - s;
  int p0 = base + excl;
  int p1 = p0 + c0;
  cur[2 * t] = p0; cur[2 * t + 1] = p1;
  int node = (k << BSHIFT) + 2 * t;
  if (node < N_NODES)     rowp[node]     = p0;
  if (node + 1 < N_NODES) rowp[node + 1] = p1;
  if (k == NBUCK - 1 && t == 0) rowp[N_NODES] = E_TOT;
  __syncthreads();
  for (int i = base + t; i < end; i += 256) {
    unsigned p = ebuf[i];
    int pos = atomicAdd(&cur[p >> 17], 1);
    ssrc[pos] = (int)(p & 0x1FFFFu);
  }
}

// ============================ W1 -> fragment-ordered bf16 hi/lo ============================

__global__ void k_w1frag(const float* __restrict__ W1, short* __restrict__ w1fh,
                         short* __restrict__ w1fl) {
  int idx = blockIdx.x * blockDim.x + threadIdx.x;
  if (idx >= N_FEAT * HIDDEN) return;
  int e    = idx & 7;
  int lane = (idx >> 3) & 63;
  int ct   = (idx >> 9) & 3;
  int ks   = idx >> 11;
  int col = ct * 16 + (lane & 15);
  int k   = ks * 32 + (lane >> 4) * 8 + e;
  unsigned short h, l;
  f2bf2(W1[k * HIDDEN + col], h, l);
  w1fh[idx] = (short)h;
  w1fl[idx] = (short)l;
}

// ============================ Layer 1 GEMM: h1 = x @ W1 (split-bf16 MFMA) ============================

__global__ __launch_bounds__(256) void k_gemm1(const float* __restrict__ x,
                                               const short* __restrict__ w1fh,
                                               const short* __restrict__ w1fl,
                                               float* __restrict__ h1) {
  int t = threadIdx.x;
  int w = t >> 6, l = t & 63;
  int n0 = blockIdx.x * 128 + w * 32;
  int r0 = l & 15;
  int kq8 = (l >> 4) * 8;
  const float* pA = x + (size_t)(n0 + r0) * N_FEAT + kq8;
  const float* pB = x + (size_t)(n0 + 16 + r0) * N_FEAT + kq8;
  bool vA = (n0 + r0) < N_NODES;
  bool vB = (n0 + 16 + r0) < N_NODES;

  f32x4 acc[2][4];
#pragma unroll
  for (int i = 0; i < 2; ++i)
#pragma unroll
    for (int j = 0; j < 4; ++j) acc[i][j] = (f32x4){0.f, 0.f, 0.f, 0.f};

#pragma unroll 2
  for (int gks = 0; gks < 16; ++gks) {
    int boff = (gks * 2048) + l * 8;
    short8_t bh[4], bl[4];
#pragma unroll
    for (int ct = 0; ct < 4; ++ct) {
      bh[ct] = *(const short8_t*)(w1fh + boff + ct * 512);
      bl[ct] = *(const short8_t*)(w1fl + boff + ct * 512);
    }
    float4 a0 = make_float4(0.f, 0.f, 0.f, 0.f), a1 = a0, c0 = a0, c1 = a0;
    if (vA) {
      const float4* p = (const float4*)(pA + gks * 32);
      a0 = p[0]; a1 = p[1];
    }
    if (vB) {
      const float4* p = (const float4*)(pB + gks * 32);
      c0 = p[0]; c1 = p[1];
    }
    short8_t ahA, alA, ahB, alB;
    cvt8(a0, a1, ahA, alA);
    cvt8(c0, c1, ahB, alB);
#pragma unroll
    for (int ct = 0; ct < 4; ++ct) {
      acc[0][ct] = __builtin_amdgcn_mfma_f32_16x16x32_bf16(ahA, bh[ct], acc[0][ct], 0, 0, 0);
      acc[0][ct] = __builtin_amdgcn_mfma_f32_16x16x32_bf16(ahA, bl[ct], acc[0][ct], 0, 0, 0);
      acc[0][ct] = __builtin_amdgcn_mfma_f32_16x16x32_bf16(alA, bh[ct], acc[0][ct], 0, 0, 0);
      acc[1][ct] = __builtin_amdgcn_mfma_f32_16x16x32_bf16(ahB, bh[ct], acc[1][ct], 0, 0, 0);
      acc[1][ct] = __builtin_amdgcn_mfma_f32_16x16x32_bf16(ahB, bl[ct], acc[1][ct], 0, 0, 0);
      acc[1][ct] = __builtin_amdgcn_mfma_f32_16x16x32_bf16(alB, bh[ct], acc[1][ct], 0, 0, 0);
    }
  }
#pragma unroll
  for (int rtl = 0; rtl < 2; ++rtl) {
    int rbase = n0 + rtl * 16 + (l >> 4) * 4;
    int col0 = l & 15;
#pragma unroll
    for (int ct = 0; ct < 4; ++ct) {
      int col = ct * 16 + col0;
#pragma unroll
      for (int r = 0; r < 4; ++r) {
        int node = rbase + r;
        if (node < N_NODES) h1[(size_t)node * HIDDEN + col] = acc[rtl][ct][r];
      }
    }
  }
}

// ============================ layer-1 attention coefficients ============================

__global__ void k_att1(const float* __restrict__ h1, const float* __restrict__ att_src,
                       const float* __restrict__ att_dst, float* __restrict__ a_src,
                       float* __restrict__ a_dst) {
  int i = blockIdx.x * blockDim.x + threadIdx.x;   // i = node*8 + head
  if (i >= N_NODES * HEADS) return;
  int h = i & 7;
  const float4* hp = (const float4*)(h1 + (size_t)i * F_HEAD);
  float4 v0 = hp[0], v1 = hp[1];
  const float4* sp = (const float4*)(att_src + h * F_HEAD);
  const float4* dp = (const float4*)(att_dst + h * F_HEAD);
  float4 s0 = sp[0], s1 = sp[1], d0 = dp[0], d1 = dp[1];
  float as = v0.x * s0.x + v0.y * s0.y + v0.z * s0.z + v0.w * s0.w +
             v1.x * s1.x + v1.y * s1.y + v1.z * s1.z + v1.w * s1.w;
  float ad = v0.x * d0.x + v0.y * d0.y + v0.z * d0.z + v0.w * d0.w +
             v1.x * d1.x + v1.y * d1.y + v1.z * d1.z + v1.w * d1.w;
  a_src[i] = as;
  a_dst[i] = ad;
}

// ============================ layer-1 edge softmax + aggregate + layer-2 projection ============
// One wave per dst node, barrier-free (per-wave LDS slices, wave-internal lgkmcnt fences).
// Ends by projecting the out1 row through W2 -> h2, a_src2, a_dst2 (out1 never materialized).

__global__ __launch_bounds__(256) void k_edge1(const int* __restrict__ rowp,
                                               const int* __restrict__ ssrc,
                                               const float* __restrict__ a_src,
                                               const float* __restrict__ a_dst,
                                               const float* __restrict__ h1,
                                               const float* __restrict__ b1,
                                               const float* __restrict__ W2,
                                               const float* __restrict__ att_src2,
                                               const float* __restrict__ att_dst2,
                                               float* __restrict__ h2,
                                               float* __restrict__ a_src2,
                                               float* __restrict__ a_dst2) {
  __shared__ __align__(16) float w2s[HIDDEN * N_CLASSES];   // 10 KB
  __shared__ float as2s[N_CLASSES], ad2s[N_CLASSES];
  __shared__ float exs[4][64 * 9];
  __shared__ int   srcs[4][64];
  __shared__ float orow[4][64];
  int t = threadIdx.x;
  for (int i = t; i < HIDDEN * N_CLASSES; i += 256) w2s[i] = W2[i];
  if (t < N_CLASSES) { as2s[t] = att_src2[t]; ad2s[t] = att_dst2[t]; }
  __syncthreads();                       // once; all waves reach before divergence

  int wv = t >> 6, lane = t & 63;
  int node = blockIdx.x * 4 + wv;        // grid = N/4 exactly
  int s0 = rowp[node];
  int s1 = rowp[node + 1];

  float ad[8];
  {
    float4 d0 = *(const float4*)(a_dst + (size_t)node * 8);
    float4 d1 = *(const float4*)(a_dst + (size_t)node * 8 + 4);
    ad[0] = d0.x; ad[1] = d0.y; ad[2] = d0.z; ad[3] = d0.w;
    ad[4] = d1.x; ad[5] = d1.y; ad[6] = d1.z; ad[7] = d1.w;
  }
  float accv = 0.f, accv2 = 0.f, dsum = 0.f, dsum2 = 0.f;
  int hof = lane >> 3;

  for (int base = s0; base < s1; base += 64) {
    int cn = s1 - base;
    cn = cn > 64 ? 64 : cn;
    asm volatile("" ::: "memory");       // keep prev-chunk LDS reads before new writes
    if (lane < cn) {
      int sid = ssrc[base + lane];
      float4 A0 = *(const float4*)(a_src + (size_t)sid * 8);
      float4 A1 = *(const float4*)(a_src + (size_t)sid * 8 + 4);
      float ea[8] = {A0.x + ad[0], A0.y + ad[1], A0.z + ad[2], A0.w + ad[3],
                     A1.x + ad[4], A1.y + ad[5], A1.z + ad[6], A1.w + ad[7]};
      srcs[wv][lane] = sid;
#pragma unroll
      for (int h = 0; h < 8; ++h) {
        float e = ea[h];
        e = e > 0.f ? e : 0.2f * e;      // leaky_relu
        exs[wv][lane * 9 + h] = expf(e);
      }
    }
    // wave-internal fence: writes visible to all lanes of this wave
    asm volatile("s_waitcnt lgkmcnt(0)" ::: "memory");
    int j = 0;
    for (; j + 1 < cn; j += 2) {
      float e0 = exs[wv][j * 9 + hof];
      float e1 = exs[wv][(j + 1) * 9 + hof];
      int sj0 = srcs[wv][j];
      int sj1 = srcs[wv][j + 1];
      float hv0 = h1[(size_t)sj0 * HIDDEN + lane];
      float hv1 = h1[(size_t)sj1 * HIDDEN + lane];
      accv  = fmaf(e0, hv0, accv);
      accv2 = fmaf(e1, hv1, accv2);
      dsum += e0; dsum2 += e1;
    }
    if (j < cn) {
      float e0 = exs[wv][j * 9 + hof];
      int sj0 = srcs[wv][j];
      accv = fmaf(e0, h1[(size_t)sj0 * HIDDEN + lane], accv);
      dsum += e0;
    }
  }
  accv += accv2; dsum += dsum2;
  float o = accv / (dsum + 1e-16f);
  o += b1[lane];
  o = o > 0.f ? o : expm1f(o);           // elu -> out1 row, kept in LDS only
  orow[wv][lane] = o;
  asm volatile("s_waitcnt lgkmcnt(0)" ::: "memory");

  // layer-2 projection: h2 = out1 @ W2, plus attention dots
  float hacc = 0.f;
  if (lane < N_CLASSES) {
#pragma unroll 16
    for (int k = 0; k < HIDDEN; ++k)
      hacc = fmaf(orow[wv][k], w2s[k * N_CLASSES + lane], hacc);
  }
  float pas = (lane < N_CLASSES) ? hacc * as2s[lane] : 0.f;
  float pad = (lane < N_CLASSES) ? hacc * ad2s[lane] : 0.f;
#pragma unroll
  for (int off = 1; off < 64; off <<= 1) {
    pas += __shfl_xor(pas, off);
    pad += __shfl_xor(pad, off);
  }
  if (lane < N_CLASSES) h2[(size_t)node * N_CLASSES + lane] = hacc;
  if (lane == 0) { a_src2[node] = pas; a_dst2[node] = pad; }
}

// ============================ layer-2 edge softmax + aggregate ============================

__global__ __launch_bounds__(256) void k_edge2(const int* __restrict__ rowp,
                                               const int* __restrict__ ssrc,
                                               const float* __restrict__ a_src,
                                               const float* __restrict__ a_dst,
                                               const float* __restrict__ h2,
                                               const float* __restrict__ b2,
                                               float* __restrict__ out) {
  __shared__ float exs[4][64];
  __shared__ int   srcs[4][64];
  int t = threadIdx.x;
  int wv = t >> 6, lane = t & 63;
  int node = blockIdx.x * 4 + wv;
  int s0 = rowp[node];
  int s1 = rowp[node + 1];

  float adv = a_dst[node];
  float accv = 0.f, accv2 = 0.f, dsum = 0.f, dsum2 = 0.f;

  for (int base = s0; base < s1; base += 64) {
    int cn = s1 - base;
    cn = cn > 64 ? 64 : cn;
    asm volatile("" ::: "memory");
    if (lane < cn) {
      int sid = ssrc[base + lane];
      float e = a_src[sid] + adv;
      e = e > 0.f ? e : 0.2f * e;
      srcs[wv][lane] = sid;
      exs[wv][lane] = expf(e);
    }
    asm volatile("s_waitcnt lgkmcnt(0)" ::: "memory");
    int j = 0;
    for (; j + 1 < cn; j += 2) {
      float e0 = exs[wv][j];
      float e1 = exs[wv][j + 1];
      dsum += e0; dsum2 += e1;
      if (lane < N_CLASSES) {
        int sj0 = srcs[wv][j];
        int sj1 = srcs[wv][j + 1];
        accv  = fmaf(e0, h2[(size_t)sj0 * N_CLASSES + lane], accv);
        accv2 = fmaf(e1, h2[(size_t)sj1 * N_CLASSES + lane], accv2);
      }
    }
    if (j < cn) {
      float e0 = exs[wv][j];
      dsum += e0;
      if (lane < N_CLASSES) {
        int sj0 = srcs[wv][j];
        accv = fmaf(e0, h2[(size_t)sj0 * N_CLASSES + lane], accv);
      }
    }
  }
  accv += accv2; dsum += dsum2;
  if (lane < N_CLASSES)
    out[(size_t)node * N_CLASSES + lane] = accv / (dsum + 1e-16f) + b2[lane];
}

// ============================ launch ============================

extern "C" void kernel_launch(void* const* d_in, const int* in_sizes, int n_in,
                              void* d_out, int out_size, void* d_ws, size_t ws_size,
                              hipStream_t stream) {
  const float* x        = (const float*)d_in[0];
  const int*   ei       = (const int*)d_in[1];
  const float* W1       = (const float*)d_in[2];
  const float* att_src1 = (const float*)d_in[3];
  const float* att_dst1 = (const float*)d_in[4];
  const float* b1       = (const float*)d_in[5];
  const float* W2       = (const float*)d_in[6];
  const float* att_src2 = (const float*)d_in[7];
  const float* att_dst2 = (const float*)d_in[8];
  const float* b2       = (const float*)d_in[9];
  float* out = (float*)d_out;

  char* w = (char*)d_ws;
  float* h1     = (float*)(w);                    // 25.6 MB
  float* h2     = (float*)(w + 25600000);         // 16 MB
  float* a_src1 = (float*)(w + 51200000);         //  3.2 MB
  float* a_dst1 = (float*)(w + 54400000);         //  3.2 MB
  int*   rowp   = (int*)(w + 57600000);           //  400 KB
  int*   ssrc   = (int*)(w + 58000128);           //  6.8 MB
  short* w1fh   = (short*)(w + 64800128);         //   64 KB
  short* w1fl   = (short*)(w + 64865664);         //   64 KB
  float* a_src2 = (float*)(w + 66000000);         //  400 KB
  float* a_dst2 = (float*)(w + 66400128);         //  400 KB
  int*   btot   = (int*)(w + 66800256);           //  784 B
  int*   bbase  = (int*)(w + 66801280);           //  788 B
  // build-time aliases (dead before their region's writer runs):
  unsigned* ebuf = (unsigned*)(w);                //  6.8 MB, aliases h1
  int*   ghT    = (int*)(w + 25600000);           //  200 KB, aliases h2

  // --- W1 fragment precompute + CSR build ---
  k_w1frag<<<(N_FEAT * HIDDEN + 255) / 256, 256, 0, stream>>>(W1, w1fh, w1fl);
  k_bhist<<<SC_NBLK, 256, 0, stream>>>(ei, ghT);
  k_scan1<<<NBUCK, 256, 0, stream>>>(ghT, btot);
  k_scan2<<<1, 256, 0, stream>>>(btot, bbase);
  k_bscatter<<<SC_NBLK, 256, 0, stream>>>(ei, ghT, bbase, ebuf);
  k_fine<<<NBUCK, 256, 0, stream>>>(ebuf, bbase, rowp, ssrc);

  // --- layer 1 (+ fused layer-2 projection) ---
  k_gemm1<<<(N_NODES + 127) / 128, 256, 0, stream>>>(x, w1fh, w1fl, h1);
  k_att1<<<(N_NODES * HEADS + 255) / 256, 256, 0, stream>>>(h1, att_src1, att_dst1, a_src1, a_dst1);
  k_edge1<<<N_NODES / 4, 256, 0, stream>>>(rowp, ssrc, a_src1, a_dst1, h1, b1,
                                           W2, att_src2, att_dst2, h2, a_src2, a_dst2);

  // --- layer 2 ---
  k_edge2<<<N_NODES / 4, 256, 0, stream>>>(rowp, ssrc, a_src2, a_dst2, h2, b2, out);
}